// Round 1
// baseline (1019.176 us; speedup 1.0000x reference)
//
#include <hip/hip_runtime.h>
#include <math.h>

#define NN 10000
#define EE 160000
#define GG 64
#define FIN 128
#define HH 256
#define ZW 512 /* HEADS*H */

// ---------------- graph preprocessing ----------------

__global__ void count_deg_kernel(const int* __restrict__ src, const int* __restrict__ dst,
                                 int* deg_src, int* deg_dst) {
  int e = blockIdx.x * blockDim.x + threadIdx.x;
  if (e < EE) {
    atomicAdd(&deg_src[src[e]], 1);
    atomicAdd(&deg_dst[dst[e]], 1);
  }
}

__global__ void norms_bounds_kernel(const int* __restrict__ deg_src, const int* __restrict__ deg_dst,
                                    const int* __restrict__ gid,
                                    float* dsrc, float* ddst, int* gstart) {
  int n = blockIdx.x * blockDim.x + threadIdx.x;
  if (n < NN) {
    int a = deg_src[n]; if (a < 1) a = 1;
    int b = deg_dst[n]; if (b < 1) b = 1;
    dsrc[n] = 1.0f / sqrtf((float)a);
    ddst[n] = 1.0f / sqrtf((float)b);
    if (n == 0) gstart[gid[0]] = 0;
    else if (gid[n] != gid[n - 1]) gstart[gid[n]] = n;
    if (n == NN - 1) gstart[GG] = NN;
  }
}

// exclusive scan of deg_dst -> row_ptr[0..NN]  (single block, 1024 threads)
__global__ void scan_kernel(const int* __restrict__ deg, int* row_ptr) {
  __shared__ int sd[1024];
  __shared__ int carry;
  if (threadIdx.x == 0) { carry = 0; row_ptr[0] = 0; }
  __syncthreads();
  for (int base = 0; base < NN; base += 1024) {
    int i = base + threadIdx.x;
    int v = (i < NN) ? deg[i] : 0;
    sd[threadIdx.x] = v;
    __syncthreads();
    for (int off = 1; off < 1024; off <<= 1) {
      int t = (threadIdx.x >= off) ? sd[threadIdx.x - off] : 0;
      __syncthreads();
      sd[threadIdx.x] += t;
      __syncthreads();
    }
    if (i < NN) row_ptr[i + 1] = carry + sd[threadIdx.x];
    __syncthreads();
    if (threadIdx.x == 0) carry += sd[1023];
    __syncthreads();
  }
}

__global__ void fill_csr_kernel(const int* __restrict__ src, const int* __restrict__ dst,
                                const int* __restrict__ row_ptr, int* fill, int* csr_src) {
  int e = blockIdx.x * blockDim.x + threadIdx.x;
  if (e < EE) {
    int d = dst[e];
    int p = atomicAdd(&fill[d], 1);
    csr_src[row_ptr[d] + p] = src[e];
  }
}

// deterministic row order: insertion-sort each row ascending by src id
__global__ void sort_rows_kernel(const int* __restrict__ row_ptr, int* csr_src) {
  int n = blockIdx.x * blockDim.x + threadIdx.x;
  if (n < NN) {
    int s0 = row_ptr[n], s1 = row_ptr[n + 1];
    for (int i = s0 + 1; i < s1; i++) {
      int v = csr_src[i];
      int j = i - 1;
      while (j >= s0 && csr_src[j] > v) { csr_src[j + 1] = csr_src[j]; j--; }
      csr_src[j + 1] = v;
    }
  }
}

// ---------------- GCN aggregate: out[n][f] = ddst[n] * sum_e dsrc[s]*x[s][f] ----------------
__global__ void gcn_agg_kernel(const float* __restrict__ x, const float* __restrict__ dsrc,
                               const float* __restrict__ ddst, const int* __restrict__ row_ptr,
                               const int* __restrict__ csr_src, float* __restrict__ out, int F) {
  int n = blockIdx.x;
  int f = threadIdx.x;
  int s0 = row_ptr[n], s1 = row_ptr[n + 1];
  float acc = 0.f;
  for (int e = s0; e < s1; e++) {
    int s = csr_src[e];
    acc += dsrc[s] * x[(size_t)s * F + f];
  }
  out[(size_t)n * F + f] = acc * ddst[n];
}

// ---------------- fp32 tiled GEMM: C[M,Nc] = act(A[M,K] @ W[K,Nc] + bias) ----------------
#define GT_M 64
#define GT_N 64
#define GT_K 16
__global__ __launch_bounds__(256) void gemm_bias_act(
    const float* __restrict__ A, const float* __restrict__ W,
    const float* __restrict__ bias, float* __restrict__ C,
    int M, int K, int Nc, int relu) {
  __shared__ float As[GT_K][GT_M + 4];
  __shared__ float Bs[GT_K][GT_N];
  int tid = threadIdx.x;
  int tx = tid & 15, ty = tid >> 4;
  int row0 = blockIdx.x * GT_M;
  int col0 = blockIdx.y * GT_N;
  float acc[4][4] = {};
  for (int k0 = 0; k0 < K; k0 += GT_K) {
    // A tile 64x16, one float4 per thread
    {
      int r = tid >> 2, kq = tid & 3;
      int gr = row0 + r;
      float4 v = make_float4(0.f, 0.f, 0.f, 0.f);
      if (gr < M) v = *(const float4*)&A[(size_t)gr * K + k0 + kq * 4];
      As[kq * 4 + 0][r] = v.x;
      As[kq * 4 + 1][r] = v.y;
      As[kq * 4 + 2][r] = v.z;
      As[kq * 4 + 3][r] = v.w;
    }
    // B tile 16x64, one float4 per thread
    {
      int r = tid >> 4, cq = tid & 15;
      float4 v = *(const float4*)&W[(size_t)(k0 + r) * Nc + col0 + cq * 4];
      *(float4*)&Bs[r][cq * 4] = v;
    }
    __syncthreads();
#pragma unroll
    for (int k = 0; k < GT_K; k++) {
      float4 a = *(const float4*)&As[k][ty * 4];
      float4 b = *(const float4*)&Bs[k][tx * 4];
      acc[0][0] += a.x * b.x; acc[0][1] += a.x * b.y; acc[0][2] += a.x * b.z; acc[0][3] += a.x * b.w;
      acc[1][0] += a.y * b.x; acc[1][1] += a.y * b.y; acc[1][2] += a.y * b.z; acc[1][3] += a.y * b.w;
      acc[2][0] += a.z * b.x; acc[2][1] += a.z * b.y; acc[2][2] += a.z * b.z; acc[2][3] += a.z * b.w;
      acc[3][0] += a.w * b.x; acc[3][1] += a.w * b.y; acc[3][2] += a.w * b.z; acc[3][3] += a.w * b.w;
    }
    __syncthreads();
  }
#pragma unroll
  for (int i = 0; i < 4; i++) {
    int gr = row0 + ty * 4 + i;
    if (gr < M) {
#pragma unroll
      for (int j = 0; j < 4; j++) {
        int gc = col0 + tx * 4 + j;
        float v = acc[i][j] + (bias ? bias[gc] : 0.f);
        if (relu) v = fmaxf(v, 0.f);
        C[(size_t)gr * Nc + gc] = v;
      }
    }
  }
}

// ---------------- GAT node scores: asrc[n][h]=sum_f z*al, adst[n][h]=sum_f z*ar ----------------
__global__ __launch_bounds__(256) void gat_scores_kernel(
    const float* __restrict__ z, const float* __restrict__ al, const float* __restrict__ ar,
    float* __restrict__ asrc, float* __restrict__ adst) {
  int n = blockIdx.x;
  int f = threadIdx.x;
  __shared__ float sp[4], sq[4];
  for (int h = 0; h < 2; h++) {
    float zv = z[(size_t)n * ZW + h * HH + f];
    float p = zv * al[h * HH + f];
    float q = zv * ar[h * HH + f];
    for (int off = 32; off > 0; off >>= 1) {
      p += __shfl_down(p, off);
      q += __shfl_down(q, off);
    }
    int w = f >> 6;
    if ((f & 63) == 0) { sp[w] = p; sq[w] = q; }
    __syncthreads();
    if (f == 0) {
      asrc[n * 2 + h] = sp[0] + sp[1] + sp[2] + sp[3];
      adst[n * 2 + h] = sq[0] + sq[1] + sq[2] + sq[3];
    }
    __syncthreads();
  }
}

// ---------------- GAT aggregate + edge softmax + relu + head-mean ----------------
__global__ __launch_bounds__(512) void gat_agg_kernel(
    const float* __restrict__ z, const float* __restrict__ asrc, const float* __restrict__ adst,
    const float* __restrict__ b, const int* __restrict__ row_ptr, const int* __restrict__ csr_src,
    float* __restrict__ out) {
  int n = blockIdx.x;
  int tid = threadIdx.x;
  int h = tid >> 8;      // 0..1
  int f = tid & 255;     // 0..255
  int s0 = row_ptr[n], s1 = row_ptr[n + 1];
  float an = adst[n * 2 + h];
  float m = -INFINITY;
  for (int e = s0; e < s1; e++) {
    int s = csr_src[e];
    float ev = asrc[s * 2 + h] + an;
    ev = (ev > 0.f) ? ev : 0.2f * ev;
    m = fmaxf(m, ev);
  }
  float sum = 0.f, acc = 0.f;
  for (int e = s0; e < s1; e++) {
    int s = csr_src[e];
    float ev = asrc[s * 2 + h] + an;
    ev = (ev > 0.f) ? ev : 0.2f * ev;
    float w = __expf(ev - m);
    sum += w;
    acc += w * z[(size_t)s * ZW + h * HH + f];
  }
  float o = (s1 > s0) ? (acc / sum) : 0.f;
  float r = fmaxf(o + b[h * HH + f], 0.f);
  __shared__ float lds[ZW];
  lds[tid] = r;
  __syncthreads();
  if (tid < HH) out[(size_t)n * HH + tid] = 0.5f * (lds[tid] + lds[tid + HH]);
}

// ---------------- per-graph readout: out[g][0:256]=avg, [256:512]=max ----------------
__global__ __launch_bounds__(256) void readout_kernel(const float* __restrict__ x,
                                                      const int* __restrict__ gstart,
                                                      float* __restrict__ out) {
  int g = blockIdx.x;
  int f = threadIdx.x;
  int n0 = gstart[g], n1 = gstart[g + 1];
  float s = 0.f, m = -INFINITY;
  for (int n = n0; n < n1; n++) {
    float v = x[(size_t)n * HH + f];
    s += v;
    m = fmaxf(m, v);
  }
  out[g * 512 + f] = s / (float)(n1 - n0);
  out[g * 512 + 256 + f] = m;
}

// ---------------- assemble merged[G,1024] ----------------
__global__ void assemble_kernel(const float* __restrict__ r1, const float* __restrict__ r2,
                                const float* __restrict__ r3, const float* __restrict__ rg2,
                                const float* __restrict__ rg3, float* __restrict__ merged) {
  int i = blockIdx.x * blockDim.x + threadIdx.x;
  if (i >= GG * 512) return;
  int g = i >> 9, c = i & 511;
  float spec = r1[i] + r2[i] + r3[i];
  float s3 = (c < 256) ? rg2[g * 512 + c] : rg3[i];  // s3 = [avg(g2) || max(g3)]
  float spat = r1[i] + rg2[i] + s3;
  merged[g * 1024 + c] = spec;
  merged[g * 1024 + 512 + c] = spat;
}

// ---------------- FC head: relu(merged@W1+b1) @ W2 + b2 -> sigmoid ----------------
__global__ __launch_bounds__(128) void fc_head_kernel(
    const float* __restrict__ merged, const float* __restrict__ W1, const float* __restrict__ b1,
    const float* __restrict__ W2, const float* __restrict__ b2, float* __restrict__ out) {
  int g = blockIdx.x;
  int t = threadIdx.x;
  __shared__ float row[1024];
  __shared__ float f1[128];
  for (int i = t; i < 1024; i += 128) row[i] = merged[g * 1024 + i];
  __syncthreads();
  float acc = b1[t];
  for (int k = 0; k < 1024; k++) acc += row[k] * W1[k * 128 + t];
  f1[t] = fmaxf(acc, 0.f);
  __syncthreads();
  if (t < 2) {
    float a = b2[t];
    for (int k = 0; k < 128; k++) a += f1[k] * W2[k * 2 + t];
    out[g * 2 + t] = 1.f / (1.f + expf(-a));
  }
}

extern "C" void kernel_launch(void* const* d_in, const int* in_sizes, int n_in,
                              void* d_out, int out_size, void* d_ws, size_t ws_size,
                              hipStream_t stream) {
  const float* h      = (const float*)d_in[0];
  const int*   src    = (const int*)d_in[1];
  const int*   dst    = (const int*)d_in[2];
  const int*   gid    = (const int*)d_in[3];
  const float* gcn1_W = (const float*)d_in[4];  const float* gcn1_b = (const float*)d_in[5];
  const float* gcn2_W = (const float*)d_in[6];  const float* gcn2_b = (const float*)d_in[7];
  const float* gcn3_W = (const float*)d_in[8];  const float* gcn3_b = (const float*)d_in[9];
  const float* gat1_W = (const float*)d_in[10]; const float* gat1_al = (const float*)d_in[11];
  const float* gat1_ar= (const float*)d_in[12]; const float* gat1_b = (const float*)d_in[13];
  const float* gat2_W = (const float*)d_in[14]; const float* gat2_al = (const float*)d_in[15];
  const float* gat2_ar= (const float*)d_in[16]; const float* gat2_b = (const float*)d_in[17];
  const float* gat3_W = (const float*)d_in[18]; const float* gat3_al = (const float*)d_in[19];
  const float* gat3_ar= (const float*)d_in[20]; const float* gat3_b = (const float*)d_in[21];
  const float* fc1_W  = (const float*)d_in[22]; const float* fc1_b = (const float*)d_in[23];
  const float* fc2_W  = (const float*)d_in[24]; const float* fc2_b = (const float*)d_in[25];

  char* ws = (char*)d_ws;
  size_t off = 0;
  auto alloc = [&](size_t bytes) -> void* {
    void* p = ws + off;
    off += (bytes + 255) & ~(size_t)255;
    return p;
  };
  float* A       = (float*)alloc((size_t)NN * HH * 4);
  float* Bbuf    = (float*)alloc((size_t)NN * HH * 4);
  float* Z       = (float*)alloc((size_t)NN * ZW * 4);
  int*   row_ptr = (int*)alloc((NN + 1) * 4);
  int*   csr_src = (int*)alloc((size_t)EE * 4);
  int*   meta    = (int*)alloc((size_t)3 * NN * 4);  // deg_src | deg_dst | fill
  int*   deg_src = meta;
  int*   deg_dst = meta + NN;
  int*   fill    = meta + 2 * NN;
  float* dsrc    = (float*)alloc(NN * 4);
  float* ddst    = (float*)alloc(NN * 4);
  int*   gstart  = (int*)alloc((GG + 1) * 4);
  float* asrc    = (float*)alloc(NN * 2 * 4);
  float* adst    = (float*)alloc(NN * 2 * 4);
  float* r1      = (float*)alloc(GG * 512 * 4);
  float* r2      = (float*)alloc(GG * 512 * 4);
  float* r3      = (float*)alloc(GG * 512 * 4);
  float* rg2     = (float*)alloc(GG * 512 * 4);
  float* rg3     = (float*)alloc(GG * 512 * 4);
  float* merged  = (float*)alloc(GG * 1024 * 4);

  const int MB = (NN + GT_M - 1) / GT_M;  // 157

  // preprocessing
  hipMemsetAsync(meta, 0, (size_t)3 * NN * 4, stream);
  count_deg_kernel<<<(EE + 255) / 256, 256, 0, stream>>>(src, dst, deg_src, deg_dst);
  norms_bounds_kernel<<<(NN + 255) / 256, 256, 0, stream>>>(deg_src, deg_dst, gid, dsrc, ddst, gstart);
  scan_kernel<<<1, 1024, 0, stream>>>(deg_dst, row_ptr);
  fill_csr_kernel<<<(EE + 255) / 256, 256, 0, stream>>>(src, dst, row_ptr, fill, csr_src);
  sort_rows_kernel<<<(NN + 255) / 256, 256, 0, stream>>>(row_ptr, csr_src);

  // GCN1: agg(h) -> Z[.,128]; relu(Z@W+b) -> A; readout -> r1
  gcn_agg_kernel<<<NN, FIN, 0, stream>>>(h, dsrc, ddst, row_ptr, csr_src, Z, FIN);
  gemm_bias_act<<<dim3(MB, HH / GT_N), 256, 0, stream>>>(Z, gcn1_W, gcn1_b, A, NN, FIN, HH, 1);
  readout_kernel<<<GG, HH, 0, stream>>>(A, gstart, r1);
  // GCN2
  gcn_agg_kernel<<<NN, HH, 0, stream>>>(A, dsrc, ddst, row_ptr, csr_src, Z, HH);
  gemm_bias_act<<<dim3(MB, HH / GT_N), 256, 0, stream>>>(Z, gcn2_W, gcn2_b, Bbuf, NN, HH, HH, 1);
  readout_kernel<<<GG, HH, 0, stream>>>(Bbuf, gstart, r2);
  // GCN3
  gcn_agg_kernel<<<NN, HH, 0, stream>>>(Bbuf, dsrc, ddst, row_ptr, csr_src, Z, HH);
  gemm_bias_act<<<dim3(MB, HH / GT_N), 256, 0, stream>>>(Z, gcn3_W, gcn3_b, A, NN, HH, HH, 1);
  readout_kernel<<<GG, HH, 0, stream>>>(A, gstart, r3);

  // GAT1: z = h@W -> Z; scores; aggregate -> Bbuf (g1)
  gemm_bias_act<<<dim3(MB, ZW / GT_N), 256, 0, stream>>>(h, gat1_W, nullptr, Z, NN, FIN, ZW, 0);
  gat_scores_kernel<<<NN, HH, 0, stream>>>(Z, gat1_al, gat1_ar, asrc, adst);
  gat_agg_kernel<<<NN, ZW, 0, stream>>>(Z, asrc, adst, gat1_b, row_ptr, csr_src, Bbuf);
  // GAT2: g2 -> A
  gemm_bias_act<<<dim3(MB, ZW / GT_N), 256, 0, stream>>>(Bbuf, gat2_W, nullptr, Z, NN, HH, ZW, 0);
  gat_scores_kernel<<<NN, HH, 0, stream>>>(Z, gat2_al, gat2_ar, asrc, adst);
  gat_agg_kernel<<<NN, ZW, 0, stream>>>(Z, asrc, adst, gat2_b, row_ptr, csr_src, A);
  readout_kernel<<<GG, HH, 0, stream>>>(A, gstart, rg2);
  // GAT3: g3 -> Bbuf
  gemm_bias_act<<<dim3(MB, ZW / GT_N), 256, 0, stream>>>(A, gat3_W, nullptr, Z, NN, HH, ZW, 0);
  gat_scores_kernel<<<NN, HH, 0, stream>>>(Z, gat3_al, gat3_ar, asrc, adst);
  gat_agg_kernel<<<NN, ZW, 0, stream>>>(Z, asrc, adst, gat3_b, row_ptr, csr_src, Bbuf);
  readout_kernel<<<GG, HH, 0, stream>>>(Bbuf, gstart, rg3);

  // merge + FC head
  assemble_kernel<<<(GG * 512 + 255) / 256, 256, 0, stream>>>(r1, r2, r3, rg2, rg3, merged);
  fc_head_kernel<<<GG, 128, 0, stream>>>(merged, fc1_W, fc1_b, fc2_W, fc2_b, (float*)d_out);
}

// Round 2
// 749.140 us; speedup vs baseline: 1.3605x; 1.3605x over previous
//
#include <hip/hip_runtime.h>
#include <math.h>

#define NN 10000
#define EE 160000
#define GG 64
#define FIN 128
#define HH 256
#define ZW 512 /* HEADS*H */
#define RS 8   /* readout slices per graph */

typedef unsigned short u16;
using bf16x8 = __attribute__((ext_vector_type(8))) short;
using f32x4 = __attribute__((ext_vector_type(4))) float;

__device__ inline u16 f2bf(float x) {
  union { float f; unsigned u; } v; v.f = x;
  unsigned r = v.u + 0x7FFF + ((v.u >> 16) & 1);
  return (u16)(r >> 16);
}

// ---------------- graph preprocessing ----------------

__global__ void count_deg_kernel(const int* __restrict__ src, const int* __restrict__ dst,
                                 int* deg_src, int* deg_dst) {
  int e = blockIdx.x * blockDim.x + threadIdx.x;
  if (e < EE) {
    atomicAdd(&deg_src[src[e]], 1);
    atomicAdd(&deg_dst[dst[e]], 1);
  }
}

__global__ void norms_bounds_kernel(const int* __restrict__ deg_src, const int* __restrict__ deg_dst,
                                    const int* __restrict__ gid,
                                    float* dsrc, float* ddst, int* gstart) {
  int n = blockIdx.x * blockDim.x + threadIdx.x;
  if (n < NN) {
    int a = deg_src[n]; if (a < 1) a = 1;
    int b = deg_dst[n]; if (b < 1) b = 1;
    dsrc[n] = 1.0f / sqrtf((float)a);
    ddst[n] = 1.0f / sqrtf((float)b);
    if (n == 0) gstart[gid[0]] = 0;
    else if (gid[n] != gid[n - 1]) gstart[gid[n]] = n;
    if (n == NN - 1) gstart[GG] = NN;
  }
}

// exclusive scan of deg_dst -> row_ptr[0..NN]  (single block, 1024 threads)
__global__ void scan_kernel(const int* __restrict__ deg, int* row_ptr) {
  __shared__ int sd[1024];
  __shared__ int carry;
  if (threadIdx.x == 0) { carry = 0; row_ptr[0] = 0; }
  __syncthreads();
  for (int base = 0; base < NN; base += 1024) {
    int i = base + threadIdx.x;
    int v = (i < NN) ? deg[i] : 0;
    sd[threadIdx.x] = v;
    __syncthreads();
    for (int off = 1; off < 1024; off <<= 1) {
      int t = (threadIdx.x >= off) ? sd[threadIdx.x - off] : 0;
      __syncthreads();
      sd[threadIdx.x] += t;
      __syncthreads();
    }
    if (i < NN) row_ptr[i + 1] = carry + sd[threadIdx.x];
    __syncthreads();
    if (threadIdx.x == 0) carry += sd[1023];
    __syncthreads();
  }
}

__global__ void fill_csr_kernel(const int* __restrict__ src, const int* __restrict__ dst,
                                const int* __restrict__ row_ptr, int* fill, int* csr_src) {
  int e = blockIdx.x * blockDim.x + threadIdx.x;
  if (e < EE) {
    int d = dst[e];
    int p = atomicAdd(&fill[d], 1);
    csr_src[row_ptr[d] + p] = src[e];
  }
}

// deterministic row order: insertion-sort each row ascending by src id
__global__ void sort_rows_kernel(const int* __restrict__ row_ptr, int* csr_src) {
  int n = blockIdx.x * blockDim.x + threadIdx.x;
  if (n < NN) {
    int s0 = row_ptr[n], s1 = row_ptr[n + 1];
    for (int i = s0 + 1; i < s1; i++) {
      int v = csr_src[i];
      int j = i - 1;
      while (j >= s0 && csr_src[j] > v) { csr_src[j + 1] = csr_src[j]; j--; }
      csr_src[j + 1] = v;
    }
  }
}

// ---------------- converts ----------------
__global__ void convert_bf16_kernel(const float* __restrict__ in, u16* __restrict__ out, int n) {
  int i = blockIdx.x * blockDim.x + threadIdx.x;
  if (i < n) out[i] = f2bf(in[i]);
}

// W[K][N] fp32 -> Wt[N][K] bf16
__global__ void transpose_bf16_kernel(const float* __restrict__ W, u16* __restrict__ Wt,
                                      int K, int N) {
  int i = blockIdx.x * blockDim.x + threadIdx.x;
  if (i < K * N) {
    int k = i / N, n = i - k * N;
    Wt[(size_t)n * K + k] = f2bf(W[i]);
  }
}

// ---------------- GCN aggregate: out[n][f] = bf16( ddst[n] * sum_e dsrc[s]*x[s][f] ) -------
__global__ void gcn_agg_kernel(const float* __restrict__ x, const float* __restrict__ dsrc,
                               const float* __restrict__ ddst, const int* __restrict__ row_ptr,
                               const int* __restrict__ csr_src, u16* __restrict__ out, int F) {
  int n = blockIdx.x;
  int f = threadIdx.x;
  int s0 = row_ptr[n], s1 = row_ptr[n + 1];
  float acc = 0.f;
  for (int e = s0; e < s1; e++) {
    int s = csr_src[e];
    acc += dsrc[s] * x[(size_t)s * F + f];
  }
  out[(size_t)n * F + f] = f2bf(acc * ddst[n]);
}

// ---------------- bf16 MFMA GEMM: C[M,Nc] = act(A[M,K] @ Wt[Nc,K]^T + bias), fp32 out -------
#define BM 128
#define BN 64
#define BK 64
#define LPAD 8  /* row stride BK+8 = 72 shorts = 144B (16B-aligned) */
__global__ __launch_bounds__(256) void gemm_mfma(
    const u16* __restrict__ A, const u16* __restrict__ Wt,
    const float* __restrict__ bias, float* __restrict__ C,
    int M, int K, int Nc, int relu) {
  __shared__ u16 As[BM][BK + LPAD];
  __shared__ u16 Bs[BN][BK + LPAD];
  int tid = threadIdx.x;
  int lane = tid & 63;
  int wid = tid >> 6;          // 4 waves
  int wm = wid & 1, wn = wid >> 1;  // 2x2 wave grid: 64 rows x 32 cols each
  int l15 = lane & 15, lg = lane >> 4;
  int row0 = blockIdx.x * BM;
  int col0 = blockIdx.y * BN;
  f32x4 acc[4][2] = {};
  for (int k0 = 0; k0 < K; k0 += BK) {
    // stage A: 128x64 bf16, 1024 16B-chunks, 4 passes
#pragma unroll
    for (int p = 0; p < 4; p++) {
      int c = p * 256 + tid;
      int r = c >> 3, k8 = c & 7;
      uint4 v = make_uint4(0, 0, 0, 0);
      int gr = row0 + r;
      if (gr < M) v = *(const uint4*)&A[(size_t)gr * K + k0 + k8 * 8];
      *(uint4*)&As[r][k8 * 8] = v;
    }
    // stage B: 64x64 bf16, 512 chunks, 2 passes (Nc always multiple of 64)
#pragma unroll
    for (int p = 0; p < 2; p++) {
      int c = p * 256 + tid;
      int r = c >> 3, k8 = c & 7;
      uint4 v = *(const uint4*)&Wt[(size_t)(col0 + r) * K + k0 + k8 * 8];
      *(uint4*)&Bs[r][k8 * 8] = v;
    }
    __syncthreads();
#pragma unroll
    for (int ks = 0; ks < BK; ks += 32) {
      bf16x8 afr[4], bfr[2];
#pragma unroll
      for (int m = 0; m < 4; m++)
        afr[m] = *(const bf16x8*)&As[wm * 64 + m * 16 + l15][ks + lg * 8];
#pragma unroll
      for (int n = 0; n < 2; n++)
        bfr[n] = *(const bf16x8*)&Bs[wn * 32 + n * 16 + l15][ks + lg * 8];
#pragma unroll
      for (int m = 0; m < 4; m++)
#pragma unroll
        for (int n = 0; n < 2; n++)
          acc[m][n] = __builtin_amdgcn_mfma_f32_16x16x32_bf16(afr[m], bfr[n], acc[m][n], 0, 0, 0);
    }
    __syncthreads();
  }
  // epilogue: C/D layout col=lane&15, row=(lane>>4)*4+j
#pragma unroll
  for (int m = 0; m < 4; m++) {
#pragma unroll
    for (int n = 0; n < 2; n++) {
      int gc = col0 + wn * 32 + n * 16 + l15;
      float bv = bias ? bias[gc] : 0.f;
#pragma unroll
      for (int j = 0; j < 4; j++) {
        int gr = row0 + wm * 64 + m * 16 + lg * 4 + j;
        if (gr < M) {
          float v = acc[m][n][j] + bv;
          if (relu) v = fmaxf(v, 0.f);
          C[(size_t)gr * Nc + gc] = v;
        }
      }
    }
  }
}

// ---------------- GAT folded score vectors: wl[h][k]=sum_f W[k][h*H+f]*al[h][f] ----------
__global__ void gat_fold_kernel(const float* __restrict__ W, const float* __restrict__ al,
                                const float* __restrict__ ar,
                                float* __restrict__ wl, float* __restrict__ wr, int K) {
  int i = blockIdx.x * blockDim.x + threadIdx.x;
  if (i >= 2 * K) return;
  int h = i / K, k = i - h * K;
  float sl = 0.f, sr = 0.f;
  for (int f = 0; f < HH; f++) {
    float wv = W[(size_t)k * ZW + h * HH + f];
    sl += wv * al[h * HH + f];
    sr += wv * ar[h * HH + f];
  }
  wl[h * K + k] = sl;
  wr[h * K + k] = sr;
}

// ---------------- node scores from x (fp32, exact rearrangement) ----------------
__global__ __launch_bounds__(64) void gat_node_scores(const float* __restrict__ x,
                                                      const float* __restrict__ wl,
                                                      const float* __restrict__ wr,
                                                      float* __restrict__ asrc,
                                                      float* __restrict__ adst, int K) {
  int n = blockIdx.x, lane = threadIdx.x;
  float a0 = 0, a1 = 0, b0 = 0, b1 = 0;
  for (int k = lane; k < K; k += 64) {
    float xv = x[(size_t)n * K + k];
    a0 += xv * wl[k];
    a1 += xv * wl[K + k];
    b0 += xv * wr[k];
    b1 += xv * wr[K + k];
  }
  for (int off = 32; off; off >>= 1) {
    a0 += __shfl_down(a0, off);
    a1 += __shfl_down(a1, off);
    b0 += __shfl_down(b0, off);
    b1 += __shfl_down(b1, off);
  }
  if (lane == 0) {
    asrc[n * 2 + 0] = a0; asrc[n * 2 + 1] = a1;
    adst[n * 2 + 0] = b0; adst[n * 2 + 1] = b1;
  }
}

// ---------------- per-edge softmax weights alpha[e][h] ----------------
__global__ void gat_alpha_kernel(const float* __restrict__ asrc, const float* __restrict__ adst,
                                 const int* __restrict__ row_ptr, const int* __restrict__ csr_src,
                                 float* __restrict__ alpha) {
  int i = blockIdx.x * blockDim.x + threadIdx.x;
  if (i >= NN * 2) return;
  int n = i >> 1, h = i & 1;
  int s0 = row_ptr[n], s1 = row_ptr[n + 1];
  float an = adst[n * 2 + h];
  float m = -INFINITY;
  for (int e = s0; e < s1; e++) {
    float ev = asrc[csr_src[e] * 2 + h] + an;
    ev = (ev > 0.f) ? ev : 0.2f * ev;
    m = fmaxf(m, ev);
  }
  float sum = 0.f;
  for (int e = s0; e < s1; e++) {
    float ev = asrc[csr_src[e] * 2 + h] + an;
    ev = (ev > 0.f) ? ev : 0.2f * ev;
    sum += __expf(ev - m);
  }
  float inv = (sum > 0.f) ? 1.f / sum : 0.f;
  for (int e = s0; e < s1; e++) {
    float ev = asrc[csr_src[e] * 2 + h] + an;
    ev = (ev > 0.f) ? ev : 0.2f * ev;
    alpha[e * 2 + h] = __expf(ev - m) * inv;
  }
}

// ---------------- GAT aggregate (single pass) + relu + head-mean ----------------
__global__ __launch_bounds__(512) void gat_agg_kernel(
    const float* __restrict__ z, const float* __restrict__ alpha, const float* __restrict__ b,
    const int* __restrict__ row_ptr, const int* __restrict__ csr_src,
    float* __restrict__ out, u16* __restrict__ out_bf) {
  int n = blockIdx.x;
  int tid = threadIdx.x;
  int h = tid >> 8;      // 0..1
  int f = tid & 255;     // 0..255
  int s0 = row_ptr[n], s1 = row_ptr[n + 1];
  float acc = 0.f;
  for (int e = s0; e < s1; e++) {
    int s = csr_src[e];
    acc += alpha[e * 2 + h] * z[(size_t)s * ZW + h * HH + f];
  }
  float r = fmaxf(acc + b[h * HH + f], 0.f);
  __shared__ float lds[ZW];
  lds[tid] = r;
  __syncthreads();
  if (tid < HH) {
    float o = 0.5f * (lds[tid] + lds[tid + HH]);
    out[(size_t)n * HH + tid] = o;
    out_bf[(size_t)n * HH + tid] = f2bf(o);
  }
}

// ---------------- two-stage per-graph readout ----------------
__global__ __launch_bounds__(256) void readout_stage1(const float* __restrict__ x,
                                                      const int* __restrict__ gstart,
                                                      float* __restrict__ partial) {
  int g = blockIdx.x, s = blockIdx.y, f = threadIdx.x;
  int n0 = gstart[g], n1 = gstart[g + 1];
  int cnt = n1 - n0;
  int chunk = (cnt + RS - 1) / RS;
  int a = n0 + s * chunk;
  int bnd = a + chunk; if (bnd > n1) bnd = n1;
  float sum = 0.f, mx = -INFINITY;
  for (int n = a; n < bnd; n++) {
    float v = x[(size_t)n * HH + f];
    sum += v;
    mx = fmaxf(mx, v);
  }
  partial[((size_t)(g * RS + s) * 2 + 0) * HH + f] = sum;
  partial[((size_t)(g * RS + s) * 2 + 1) * HH + f] = mx;
}

__global__ __launch_bounds__(512) void readout_stage2(const float* __restrict__ partial,
                                                      const int* __restrict__ gstart,
                                                      float* __restrict__ out) {
  int g = blockIdx.x, t = threadIdx.x;
  int f = t & 255, ismax = t >> 8;
  if (!ismax) {
    float s = 0.f;
    for (int k = 0; k < RS; k++) s += partial[((size_t)(g * RS + k) * 2 + 0) * HH + f];
    out[g * 512 + f] = s / (float)(gstart[g + 1] - gstart[g]);
  } else {
    float m = -INFINITY;
    for (int k = 0; k < RS; k++) m = fmaxf(m, partial[((size_t)(g * RS + k) * 2 + 1) * HH + f]);
    out[g * 512 + 256 + f] = m;
  }
}

// ---------------- assemble merged[G,1024] ----------------
__global__ void assemble_kernel(const float* __restrict__ r1, const float* __restrict__ r2,
                                const float* __restrict__ r3, const float* __restrict__ rg2,
                                const float* __restrict__ rg3, float* __restrict__ merged) {
  int i = blockIdx.x * blockDim.x + threadIdx.x;
  if (i >= GG * 512) return;
  int g = i >> 9, c = i & 511;
  float spec = r1[i] + r2[i] + r3[i];
  float s3 = (c < 256) ? rg2[g * 512 + c] : rg3[i];  // s3 = [avg(g2) || max(g3)]
  float spat = r1[i] + rg2[i] + s3;
  merged[g * 1024 + c] = spec;
  merged[g * 1024 + 512 + c] = spat;
}

// ---------------- FC head ----------------
__global__ __launch_bounds__(128) void fc_head_kernel(
    const float* __restrict__ merged, const float* __restrict__ W1, const float* __restrict__ b1,
    const float* __restrict__ W2, const float* __restrict__ b2, float* __restrict__ out) {
  int g = blockIdx.x;
  int t = threadIdx.x;
  __shared__ float row[1024];
  __shared__ float f1[128];
  for (int i = t; i < 1024; i += 128) row[i] = merged[g * 1024 + i];
  __syncthreads();
  float acc = b1[t];
  for (int k = 0; k < 1024; k++) acc += row[k] * W1[k * 128 + t];
  f1[t] = fmaxf(acc, 0.f);
  __syncthreads();
  if (t < 2) {
    float a = b2[t];
    for (int k = 0; k < 128; k++) a += f1[k] * W2[k * 2 + t];
    out[g * 2 + t] = 1.f / (1.f + expf(-a));
  }
}

extern "C" void kernel_launch(void* const* d_in, const int* in_sizes, int n_in,
                              void* d_out, int out_size, void* d_ws, size_t ws_size,
                              hipStream_t stream) {
  const float* h      = (const float*)d_in[0];
  const int*   src    = (const int*)d_in[1];
  const int*   dst    = (const int*)d_in[2];
  const int*   gid    = (const int*)d_in[3];
  const float* gcn1_W = (const float*)d_in[4];  const float* gcn1_b = (const float*)d_in[5];
  const float* gcn2_W = (const float*)d_in[6];  const float* gcn2_b = (const float*)d_in[7];
  const float* gcn3_W = (const float*)d_in[8];  const float* gcn3_b = (const float*)d_in[9];
  const float* gat1_W = (const float*)d_in[10]; const float* gat1_al = (const float*)d_in[11];
  const float* gat1_ar= (const float*)d_in[12]; const float* gat1_b = (const float*)d_in[13];
  const float* gat2_W = (const float*)d_in[14]; const float* gat2_al = (const float*)d_in[15];
  const float* gat2_ar= (const float*)d_in[16]; const float* gat2_b = (const float*)d_in[17];
  const float* gat3_W = (const float*)d_in[18]; const float* gat3_al = (const float*)d_in[19];
  const float* gat3_ar= (const float*)d_in[20]; const float* gat3_b = (const float*)d_in[21];
  const float* fc1_W  = (const float*)d_in[22]; const float* fc1_b = (const float*)d_in[23];
  const float* fc2_W  = (const float*)d_in[24]; const float* fc2_b = (const float*)d_in[25];

  char* ws = (char*)d_ws;
  size_t off = 0;
  auto alloc = [&](size_t bytes) -> void* {
    void* p = ws + off;
    off += (bytes + 255) & ~(size_t)255;
    return p;
  };
  float* A       = (float*)alloc((size_t)NN * HH * 4);   // fp32 activations
  float* Bbuf    = (float*)alloc((size_t)NN * HH * 4);
  float* Z       = (float*)alloc((size_t)NN * ZW * 4);   // GAT GEMM out
  u16*   Zagg_bf = (u16*)alloc((size_t)NN * HH * 2);     // gcn agg out (bf16)
  u16*   gbf     = (u16*)alloc((size_t)NN * HH * 2);     // gat agg out (bf16)
  u16*   h_bf    = (u16*)alloc((size_t)NN * FIN * 2);
  int*   row_ptr = (int*)alloc((NN + 1) * 4);
  int*   csr_src = (int*)alloc((size_t)EE * 4);
  int*   meta    = (int*)alloc((size_t)3 * NN * 4);  // deg_src | deg_dst | fill
  int*   deg_src = meta;
  int*   deg_dst = meta + NN;
  int*   fill    = meta + 2 * NN;
  float* dsrc    = (float*)alloc(NN * 4);
  float* ddst    = (float*)alloc(NN * 4);
  int*   gstart  = (int*)alloc((GG + 1) * 4);
  float* asrc    = (float*)alloc(NN * 2 * 4);
  float* adst    = (float*)alloc(NN * 2 * 4);
  float* alpha   = (float*)alloc((size_t)EE * 2 * 4);
  float* wl      = (float*)alloc(2 * HH * 4);
  float* wr      = (float*)alloc(2 * HH * 4);
  float* partial = (float*)alloc((size_t)GG * RS * 2 * HH * 4);
  float* r1      = (float*)alloc(GG * 512 * 4);
  float* r2      = (float*)alloc(GG * 512 * 4);
  float* r3      = (float*)alloc(GG * 512 * 4);
  float* rg2     = (float*)alloc(GG * 512 * 4);
  float* rg3     = (float*)alloc(GG * 512 * 4);
  float* merged  = (float*)alloc(GG * 1024 * 4);
  u16* gcn1_Wt = (u16*)alloc((size_t)FIN * HH * 2);
  u16* gcn2_Wt = (u16*)alloc((size_t)HH * HH * 2);
  u16* gcn3_Wt = (u16*)alloc((size_t)HH * HH * 2);
  u16* gat1_Wt = (u16*)alloc((size_t)FIN * ZW * 2);
  u16* gat2_Wt = (u16*)alloc((size_t)HH * ZW * 2);
  u16* gat3_Wt = (u16*)alloc((size_t)HH * ZW * 2);

  const int MB = (NN + BM - 1) / BM;  // 79

  // preprocessing
  hipMemsetAsync(meta, 0, (size_t)3 * NN * 4, stream);
  count_deg_kernel<<<(EE + 255) / 256, 256, 0, stream>>>(src, dst, deg_src, deg_dst);
  norms_bounds_kernel<<<(NN + 255) / 256, 256, 0, stream>>>(deg_src, deg_dst, gid, dsrc, ddst, gstart);
  scan_kernel<<<1, 1024, 0, stream>>>(deg_dst, row_ptr);
  fill_csr_kernel<<<(EE + 255) / 256, 256, 0, stream>>>(src, dst, row_ptr, fill, csr_src);
  sort_rows_kernel<<<(NN + 255) / 256, 256, 0, stream>>>(row_ptr, csr_src);

  // weight converts
  transpose_bf16_kernel<<<(FIN * HH + 255) / 256, 256, 0, stream>>>(gcn1_W, gcn1_Wt, FIN, HH);
  transpose_bf16_kernel<<<(HH * HH + 255) / 256, 256, 0, stream>>>(gcn2_W, gcn2_Wt, HH, HH);
  transpose_bf16_kernel<<<(HH * HH + 255) / 256, 256, 0, stream>>>(gcn3_W, gcn3_Wt, HH, HH);
  transpose_bf16_kernel<<<(FIN * ZW + 255) / 256, 256, 0, stream>>>(gat1_W, gat1_Wt, FIN, ZW);
  transpose_bf16_kernel<<<(HH * ZW + 255) / 256, 256, 0, stream>>>(gat2_W, gat2_Wt, HH, ZW);
  transpose_bf16_kernel<<<(HH * ZW + 255) / 256, 256, 0, stream>>>(gat3_W, gat3_Wt, HH, ZW);
  convert_bf16_kernel<<<(NN * FIN + 255) / 256, 256, 0, stream>>>(h, h_bf, NN * FIN);

  // ---- GCN1 ----
  gcn_agg_kernel<<<NN, FIN, 0, stream>>>(h, dsrc, ddst, row_ptr, csr_src, Zagg_bf, FIN);
  gemm_mfma<<<dim3(MB, HH / BN), 256, 0, stream>>>(Zagg_bf, gcn1_Wt, gcn1_b, A, NN, FIN, HH, 1);
  readout_stage1<<<dim3(GG, RS), HH, 0, stream>>>(A, gstart, partial);
  readout_stage2<<<GG, 512, 0, stream>>>(partial, gstart, r1);
  // ---- GCN2 ----
  gcn_agg_kernel<<<NN, HH, 0, stream>>>(A, dsrc, ddst, row_ptr, csr_src, Zagg_bf, HH);
  gemm_mfma<<<dim3(MB, HH / BN), 256, 0, stream>>>(Zagg_bf, gcn2_Wt, gcn2_b, Bbuf, NN, HH, HH, 1);
  readout_stage1<<<dim3(GG, RS), HH, 0, stream>>>(Bbuf, gstart, partial);
  readout_stage2<<<GG, 512, 0, stream>>>(partial, gstart, r2);
  // ---- GCN3 ----
  gcn_agg_kernel<<<NN, HH, 0, stream>>>(Bbuf, dsrc, ddst, row_ptr, csr_src, Zagg_bf, HH);
  gemm_mfma<<<dim3(MB, HH / BN), 256, 0, stream>>>(Zagg_bf, gcn3_Wt, gcn3_b, A, NN, HH, HH, 1);
  readout_stage1<<<dim3(GG, RS), HH, 0, stream>>>(A, gstart, partial);
  readout_stage2<<<GG, 512, 0, stream>>>(partial, gstart, r3);

  // ---- GAT1: input h (fp32) / h_bf ----
  gat_fold_kernel<<<(2 * FIN + 63) / 64, 64, 0, stream>>>(gat1_W, gat1_al, gat1_ar, wl, wr, FIN);
  gat_node_scores<<<NN, 64, 0, stream>>>(h, wl, wr, asrc, adst, FIN);
  gat_alpha_kernel<<<(NN * 2 + 255) / 256, 256, 0, stream>>>(asrc, adst, row_ptr, csr_src, alpha);
  gemm_mfma<<<dim3(MB, ZW / BN), 256, 0, stream>>>(h_bf, gat1_Wt, nullptr, Z, NN, FIN, ZW, 0);
  gat_agg_kernel<<<NN, ZW, 0, stream>>>(Z, alpha, gat1_b, row_ptr, csr_src, Bbuf, gbf);  // g1
  // ---- GAT2: input g1 (Bbuf / gbf) ----
  gat_fold_kernel<<<(2 * HH + 63) / 64, 64, 0, stream>>>(gat2_W, gat2_al, gat2_ar, wl, wr, HH);
  gat_node_scores<<<NN, 64, 0, stream>>>(Bbuf, wl, wr, asrc, adst, HH);
  gat_alpha_kernel<<<(NN * 2 + 255) / 256, 256, 0, stream>>>(asrc, adst, row_ptr, csr_src, alpha);
  gemm_mfma<<<dim3(MB, ZW / BN), 256, 0, stream>>>(gbf, gat2_Wt, nullptr, Z, NN, HH, ZW, 0);
  gat_agg_kernel<<<NN, ZW, 0, stream>>>(Z, alpha, gat2_b, row_ptr, csr_src, A, gbf);  // g2
  readout_stage1<<<dim3(GG, RS), HH, 0, stream>>>(A, gstart, partial);
  readout_stage2<<<GG, 512, 0, stream>>>(partial, gstart, rg2);
  // ---- GAT3: input g2 (A / gbf) ----
  gat_fold_kernel<<<(2 * HH + 63) / 64, 64, 0, stream>>>(gat3_W, gat3_al, gat3_ar, wl, wr, HH);
  gat_node_scores<<<NN, 64, 0, stream>>>(A, wl, wr, asrc, adst, HH);
  gat_alpha_kernel<<<(NN * 2 + 255) / 256, 256, 0, stream>>>(asrc, adst, row_ptr, csr_src, alpha);
  gemm_mfma<<<dim3(MB, ZW / BN), 256, 0, stream>>>(gbf, gat3_Wt, nullptr, Z, NN, HH, ZW, 0);
  gat_agg_kernel<<<NN, ZW, 0, stream>>>(Z, alpha, gat3_b, row_ptr, csr_src, Bbuf, gbf);  // g3
  readout_stage1<<<dim3(GG, RS), HH, 0, stream>>>(Bbuf, gstart, partial);
  readout_stage2<<<GG, 512, 0, stream>>>(partial, gstart, rg3);

  // merge + FC head
  assemble_kernel<<<(GG * 512 + 255) / 256, 256, 0, stream>>>(r1, r2, r3, rg2, rg3, merged);
  fc_head_kernel<<<GG, 128, 0, stream>>>(merged, fc1_W, fc1_b, fc2_W, fc2_b, (float*)d_out);
}

// Round 3
// 550.198 us; speedup vs baseline: 1.8524x; 1.3616x over previous
//
#include <hip/hip_runtime.h>
#include <math.h>

#define NN 10000
#define EE 160000
#define GG 64
#define FIN 128
#define HH 256
#define ZW 512 /* HEADS*H */
#define RS 8   /* readout slices per graph */

typedef unsigned short u16;
using bf16x8 = __attribute__((ext_vector_type(8))) short;
using f32x4 = __attribute__((ext_vector_type(4))) float;

__device__ inline u16 f2bf(float x) {
  union { float f; unsigned u; } v; v.f = x;
  unsigned r = v.u + 0x7FFF + ((v.u >> 16) & 1);
  return (u16)(r >> 16);
}
__device__ inline float bflo(unsigned pair) {
  union { unsigned u; float f; } v; v.u = pair << 16; return v.f;
}
__device__ inline float bfhi(unsigned pair) {
  union { unsigned u; float f; } v; v.u = pair & 0xFFFF0000u; return v.f;
}

// ---------------- graph preprocessing ----------------

__global__ void count_deg_kernel(const int* __restrict__ src, const int* __restrict__ dst,
                                 int* deg_src, int* deg_dst) {
  int e = blockIdx.x * blockDim.x + threadIdx.x;
  if (e < EE) {
    atomicAdd(&deg_src[src[e]], 1);
    atomicAdd(&deg_dst[dst[e]], 1);
  }
}

__global__ void norms_bounds_kernel(const int* __restrict__ deg_src, const int* __restrict__ deg_dst,
                                    const int* __restrict__ gid,
                                    float* dsrc, float* ddst, int* gstart) {
  int n = blockIdx.x * blockDim.x + threadIdx.x;
  if (n < NN) {
    int a = deg_src[n]; if (a < 1) a = 1;
    int b = deg_dst[n]; if (b < 1) b = 1;
    dsrc[n] = 1.0f / sqrtf((float)a);
    ddst[n] = 1.0f / sqrtf((float)b);
    if (n == 0) gstart[gid[0]] = 0;
    else if (gid[n] != gid[n - 1]) gstart[gid[n]] = n;
    if (n == NN - 1) gstart[GG] = NN;
  }
}

// exclusive scan of deg_dst -> row_ptr[0..NN]  (single block, 1024 threads)
__global__ void scan_kernel(const int* __restrict__ deg, int* row_ptr) {
  __shared__ int sd[1024];
  __shared__ int carry;
  if (threadIdx.x == 0) { carry = 0; row_ptr[0] = 0; }
  __syncthreads();
  for (int base = 0; base < NN; base += 1024) {
    int i = base + threadIdx.x;
    int v = (i < NN) ? deg[i] : 0;
    sd[threadIdx.x] = v;
    __syncthreads();
    for (int off = 1; off < 1024; off <<= 1) {
      int t = (threadIdx.x >= off) ? sd[threadIdx.x - off] : 0;
      __syncthreads();
      sd[threadIdx.x] += t;
      __syncthreads();
    }
    if (i < NN) row_ptr[i + 1] = carry + sd[threadIdx.x];
    __syncthreads();
    if (threadIdx.x == 0) carry += sd[1023];
    __syncthreads();
  }
}

__global__ void fill_csr_kernel(const int* __restrict__ src, const int* __restrict__ dst,
                                const int* __restrict__ row_ptr, int* fill, int* csr_src) {
  int e = blockIdx.x * blockDim.x + threadIdx.x;
  if (e < EE) {
    int d = dst[e];
    int p = atomicAdd(&fill[d], 1);
    csr_src[row_ptr[d] + p] = src[e];
  }
}

// deterministic row order: parallel rank-sort, one 64-thread block per row
__global__ __launch_bounds__(64) void sort_rows_kernel(const int* __restrict__ row_ptr,
                                                       int* csr_src) {
  int n = blockIdx.x;
  int s0 = row_ptr[n];
  int L = row_ptr[n + 1] - s0;
  if (L <= 1) return;
  __shared__ int buf[512];
  if (L <= 512) {
    for (int i = threadIdx.x; i < L; i += 64) buf[i] = csr_src[s0 + i];
    __syncthreads();
    for (int i = threadIdx.x; i < L; i += 64) {
      int v = buf[i], r = 0;
      for (int j = 0; j < L; j++) {
        int u = buf[j];
        r += (u < v) || (u == v && j < i);
      }
      csr_src[s0 + r] = v;
    }
  } else if (threadIdx.x == 0) {
    for (int i = s0 + 1; i < s0 + L; i++) {
      int v = csr_src[i], j = i - 1;
      while (j >= s0 && csr_src[j] > v) { csr_src[j + 1] = csr_src[j]; j--; }
      csr_src[j + 1] = v;
    }
  }
}

// ---------------- converts ----------------
__global__ void convert_bf16_kernel(const float* __restrict__ in, u16* __restrict__ out, int n) {
  int i = blockIdx.x * blockDim.x + threadIdx.x;
  if (i < n) out[i] = f2bf(in[i]);
}

// W[K][N] fp32 -> Wt[N][K] bf16
__global__ void transpose_bf16_kernel(const float* __restrict__ W, u16* __restrict__ Wt,
                                      int K, int N) {
  int i = blockIdx.x * blockDim.x + threadIdx.x;
  if (i < K * N) {
    int k = i / N, n = i - k * N;
    Wt[(size_t)n * K + k] = f2bf(W[i]);
  }
}

// ---------------- GCN aggregate (bf16 in/out, wave per node) ----------------
__global__ __launch_bounds__(256) void gcn_agg_kernel(
    const u16* __restrict__ xb, const float* __restrict__ dsrc, const float* __restrict__ ddst,
    const int* __restrict__ row_ptr, const int* __restrict__ csr_src,
    u16* __restrict__ out, int F) {
  int wid = threadIdx.x >> 6, lane = threadIdx.x & 63;
  int n = blockIdx.x * 4 + wid;
  if (n >= NN) return;
  int s0 = row_ptr[n], s1 = row_ptr[n + 1];
  float dd = ddst[n];
  if (F == 256) {
    int bf = lane * 4;
    float a0 = 0, a1 = 0, a2 = 0, a3 = 0;
    for (int e = s0; e < s1; e++) {
      int s = csr_src[e];
      float w = dsrc[s];
      uint2 v = *(const uint2*)&xb[(size_t)s * 256 + bf];
      a0 += w * bflo(v.x); a1 += w * bfhi(v.x);
      a2 += w * bflo(v.y); a3 += w * bfhi(v.y);
    }
    ushort4 o;
    o.x = f2bf(a0 * dd); o.y = f2bf(a1 * dd); o.z = f2bf(a2 * dd); o.w = f2bf(a3 * dd);
    *(ushort4*)&out[(size_t)n * 256 + bf] = o;
  } else {  // F == 128
    int bf = lane * 2;
    float a0 = 0, a1 = 0;
    for (int e = s0; e < s1; e++) {
      int s = csr_src[e];
      float w = dsrc[s];
      unsigned v = *(const unsigned*)&xb[(size_t)s * 128 + bf];
      a0 += w * bflo(v); a1 += w * bfhi(v);
    }
    ushort2 o;
    o.x = f2bf(a0 * dd); o.y = f2bf(a1 * dd);
    *(ushort2*)&out[(size_t)n * 128 + bf] = o;
  }
}

// ---------------- bf16 MFMA GEMM: act(A[M,K] @ Wt[Nc,K]^T + bias) -> fp32 C and/or bf16 Cb ----
#define BM 128
#define BN 64
#define BK 64
#define LPAD 8  /* row stride BK+8 = 72 shorts = 144B (16B-aligned) */
__global__ __launch_bounds__(256) void gemm_mfma(
    const u16* __restrict__ A, const u16* __restrict__ Wt,
    const float* __restrict__ bias, float* __restrict__ C, u16* __restrict__ Cb,
    int M, int K, int Nc, int relu) {
  __shared__ u16 As[BM][BK + LPAD];
  __shared__ u16 Bs[BN][BK + LPAD];
  int tid = threadIdx.x;
  int lane = tid & 63;
  int wid = tid >> 6;          // 4 waves
  int wm = wid & 1, wn = wid >> 1;  // 2x2 wave grid: 64 rows x 32 cols each
  int l15 = lane & 15, lg = lane >> 4;
  int row0 = blockIdx.x * BM;
  int col0 = blockIdx.y * BN;
  f32x4 acc[4][2] = {};
  for (int k0 = 0; k0 < K; k0 += BK) {
#pragma unroll
    for (int p = 0; p < 4; p++) {
      int c = p * 256 + tid;
      int r = c >> 3, k8 = c & 7;
      uint4 v = make_uint4(0, 0, 0, 0);
      int gr = row0 + r;
      if (gr < M) v = *(const uint4*)&A[(size_t)gr * K + k0 + k8 * 8];
      *(uint4*)&As[r][k8 * 8] = v;
    }
#pragma unroll
    for (int p = 0; p < 2; p++) {
      int c = p * 256 + tid;
      int r = c >> 3, k8 = c & 7;
      uint4 v = *(const uint4*)&Wt[(size_t)(col0 + r) * K + k0 + k8 * 8];
      *(uint4*)&Bs[r][k8 * 8] = v;
    }
    __syncthreads();
#pragma unroll
    for (int ks = 0; ks < BK; ks += 32) {
      bf16x8 afr[4], bfr[2];
#pragma unroll
      for (int m = 0; m < 4; m++)
        afr[m] = *(const bf16x8*)&As[wm * 64 + m * 16 + l15][ks + lg * 8];
#pragma unroll
      for (int n = 0; n < 2; n++)
        bfr[n] = *(const bf16x8*)&Bs[wn * 32 + n * 16 + l15][ks + lg * 8];
#pragma unroll
      for (int m = 0; m < 4; m++)
#pragma unroll
        for (int n = 0; n < 2; n++)
          acc[m][n] = __builtin_amdgcn_mfma_f32_16x16x32_bf16(afr[m], bfr[n], acc[m][n], 0, 0, 0);
    }
    __syncthreads();
  }
#pragma unroll
  for (int m = 0; m < 4; m++) {
#pragma unroll
    for (int n = 0; n < 2; n++) {
      int gc = col0 + wn * 32 + n * 16 + l15;
      float bv = bias ? bias[gc] : 0.f;
#pragma unroll
      for (int j = 0; j < 4; j++) {
        int gr = row0 + wm * 64 + m * 16 + lg * 4 + j;
        if (gr < M) {
          float v = acc[m][n][j] + bv;
          if (relu) v = fmaxf(v, 0.f);
          if (C) C[(size_t)gr * Nc + gc] = v;
          if (Cb) Cb[(size_t)gr * Nc + gc] = f2bf(v);
        }
      }
    }
  }
}

// ---------------- GAT folded score vectors ----------------
__global__ void gat_fold_kernel(const float* __restrict__ W, const float* __restrict__ al,
                                const float* __restrict__ ar,
                                float* __restrict__ wl, float* __restrict__ wr, int K) {
  int i = blockIdx.x * blockDim.x + threadIdx.x;
  if (i >= 2 * K) return;
  int h = i / K, k = i - h * K;
  float sl = 0.f, sr = 0.f;
  for (int f = 0; f < HH; f++) {
    float wv = W[(size_t)k * ZW + h * HH + f];
    sl += wv * al[h * HH + f];
    sr += wv * ar[h * HH + f];
  }
  wl[h * K + k] = sl;
  wr[h * K + k] = sr;
}

// ---------------- node scores from x (fp32, exact rearrangement) ----------------
__global__ __launch_bounds__(64) void gat_node_scores(const float* __restrict__ x,
                                                      const float* __restrict__ wl,
                                                      const float* __restrict__ wr,
                                                      float* __restrict__ asrc,
                                                      float* __restrict__ adst, int K) {
  int n = blockIdx.x, lane = threadIdx.x;
  float a0 = 0, a1 = 0, b0 = 0, b1 = 0;
  for (int k = lane; k < K; k += 64) {
    float xv = x[(size_t)n * K + k];
    a0 += xv * wl[k];
    a1 += xv * wl[K + k];
    b0 += xv * wr[k];
    b1 += xv * wr[K + k];
  }
  for (int off = 32; off; off >>= 1) {
    a0 += __shfl_down(a0, off);
    a1 += __shfl_down(a1, off);
    b0 += __shfl_down(b0, off);
    b1 += __shfl_down(b1, off);
  }
  if (lane == 0) {
    asrc[n * 2 + 0] = a0; asrc[n * 2 + 1] = a1;
    adst[n * 2 + 0] = b0; adst[n * 2 + 1] = b1;
  }
}

// ---------------- per-edge softmax weights alpha[e][h] ----------------
__global__ void gat_alpha_kernel(const float* __restrict__ asrc, const float* __restrict__ adst,
                                 const int* __restrict__ row_ptr, const int* __restrict__ csr_src,
                                 float* __restrict__ alpha) {
  int i = blockIdx.x * blockDim.x + threadIdx.x;
  if (i >= NN * 2) return;
  int n = i >> 1, h = i & 1;
  int s0 = row_ptr[n], s1 = row_ptr[n + 1];
  float an = adst[n * 2 + h];
  float m = -INFINITY;
  for (int e = s0; e < s1; e++) {
    float ev = asrc[csr_src[e] * 2 + h] + an;
    ev = (ev > 0.f) ? ev : 0.2f * ev;
    m = fmaxf(m, ev);
  }
  float sum = 0.f;
  for (int e = s0; e < s1; e++) {
    float ev = asrc[csr_src[e] * 2 + h] + an;
    ev = (ev > 0.f) ? ev : 0.2f * ev;
    sum += __expf(ev - m);
  }
  float inv = (sum > 0.f) ? 1.f / sum : 0.f;
  for (int e = s0; e < s1; e++) {
    float ev = asrc[csr_src[e] * 2 + h] + an;
    ev = (ev > 0.f) ? ev : 0.2f * ev;
    alpha[e * 2 + h] = __expf(ev - m) * inv;
  }
}

// ---------------- GAT aggregate (bf16 z, single pass) + relu + head-mean ----------------
__global__ __launch_bounds__(256) void gat_agg_kernel(
    const u16* __restrict__ zb, const float* __restrict__ alpha, const float* __restrict__ b,
    const int* __restrict__ row_ptr, const int* __restrict__ csr_src,
    float* __restrict__ out, u16* __restrict__ out_bf) {
  int n = blockIdx.x;
  int tid = threadIdx.x;
  int h = tid >> 7;       // 0..1
  int p = tid & 127;      // bf16-pair index: features 2p, 2p+1 of head h
  int s0 = row_ptr[n], s1 = row_ptr[n + 1];
  float a0 = 0.f, a1 = 0.f;
  for (int e = s0; e < s1; e++) {
    int s = csr_src[e];
    float w = alpha[e * 2 + h];
    unsigned zv = *(const unsigned*)&zb[(size_t)s * ZW + h * HH + p * 2];
    a0 += w * bflo(zv);
    a1 += w * bfhi(zv);
  }
  float r0 = fmaxf(a0 + b[h * HH + p * 2 + 0], 0.f);
  float r1 = fmaxf(a1 + b[h * HH + p * 2 + 1], 0.f);
  __shared__ float hv[2][HH];
  hv[h][p * 2 + 0] = r0;
  hv[h][p * 2 + 1] = r1;
  __syncthreads();
  float o = 0.5f * (hv[0][tid] + hv[1][tid]);
  out[(size_t)n * HH + tid] = o;
  out_bf[(size_t)n * HH + tid] = f2bf(o);
}

// ---------------- two-stage per-graph readout ----------------
__global__ __launch_bounds__(256) void readout_stage1(const float* __restrict__ x,
                                                      const int* __restrict__ gstart,
                                                      float* __restrict__ partial) {
  int g = blockIdx.x, s = blockIdx.y, f = threadIdx.x;
  int n0 = gstart[g], n1 = gstart[g + 1];
  int cnt = n1 - n0;
  int chunk = (cnt + RS - 1) / RS;
  int a = n0 + s * chunk;
  int bnd = a + chunk; if (bnd > n1) bnd = n1;
  float sum = 0.f, mx = -INFINITY;
  for (int n = a; n < bnd; n++) {
    float v = x[(size_t)n * HH + f];
    sum += v;
    mx = fmaxf(mx, v);
  }
  partial[((size_t)(g * RS + s) * 2 + 0) * HH + f] = sum;
  partial[((size_t)(g * RS + s) * 2 + 1) * HH + f] = mx;
}

__global__ __launch_bounds__(512) void readout_stage2(const float* __restrict__ partial,
                                                      const int* __restrict__ gstart,
                                                      float* __restrict__ out) {
  int g = blockIdx.x, t = threadIdx.x;
  int f = t & 255, ismax = t >> 8;
  if (!ismax) {
    float s = 0.f;
    for (int k = 0; k < RS; k++) s += partial[((size_t)(g * RS + k) * 2 + 0) * HH + f];
    out[g * 512 + f] = s / (float)(gstart[g + 1] - gstart[g]);
  } else {
    float m = -INFINITY;
    for (int k = 0; k < RS; k++) m = fmaxf(m, partial[((size_t)(g * RS + k) * 2 + 1) * HH + f]);
    out[g * 512 + 256 + f] = m;
  }
}

// ---------------- assemble merged[G,1024] ----------------
__global__ void assemble_kernel(const float* __restrict__ r1, const float* __restrict__ r2,
                                const float* __restrict__ r3, const float* __restrict__ rg2,
                                const float* __restrict__ rg3, float* __restrict__ merged) {
  int i = blockIdx.x * blockDim.x + threadIdx.x;
  if (i >= GG * 512) return;
  int g = i >> 9, c = i & 511;
  float spec = r1[i] + r2[i] + r3[i];
  float s3 = (c < 256) ? rg2[g * 512 + c] : rg3[i];  // s3 = [avg(g2) || max(g3)]
  float spat = r1[i] + rg2[i] + s3;
  merged[g * 1024 + c] = spec;
  merged[g * 1024 + 512 + c] = spat;
}

// ---------------- FC head ----------------
__global__ __launch_bounds__(128) void fc_head_kernel(
    const float* __restrict__ merged, const float* __restrict__ W1, const float* __restrict__ b1,
    const float* __restrict__ W2, const float* __restrict__ b2, float* __restrict__ out) {
  int g = blockIdx.x;
  int t = threadIdx.x;
  __shared__ float row[1024];
  __shared__ float f1[128];
  for (int i = t; i < 1024; i += 128) row[i] = merged[g * 1024 + i];
  __syncthreads();
  float acc = b1[t];
  for (int k = 0; k < 1024; k++) acc += row[k] * W1[k * 128 + t];
  f1[t] = fmaxf(acc, 0.f);
  __syncthreads();
  if (t < 2) {
    float a = b2[t];
    for (int k = 0; k < 128; k++) a += f1[k] * W2[k * 2 + t];
    out[g * 2 + t] = 1.f / (1.f + expf(-a));
  }
}

extern "C" void kernel_launch(void* const* d_in, const int* in_sizes, int n_in,
                              void* d_out, int out_size, void* d_ws, size_t ws_size,
                              hipStream_t stream) {
  const float* h      = (const float*)d_in[0];
  const int*   src    = (const int*)d_in[1];
  const int*   dst    = (const int*)d_in[2];
  const int*   gid    = (const int*)d_in[3];
  const float* gcn1_W = (const float*)d_in[4];  const float* gcn1_b = (const float*)d_in[5];
  const float* gcn2_W = (const float*)d_in[6];  const float* gcn2_b = (const float*)d_in[7];
  const float* gcn3_W = (const float*)d_in[8];  const float* gcn3_b = (const float*)d_in[9];
  const float* gat1_W = (const float*)d_in[10]; const float* gat1_al = (const float*)d_in[11];
  const float* gat1_ar= (const float*)d_in[12]; const float* gat1_b = (const float*)d_in[13];
  const float* gat2_W = (const float*)d_in[14]; const float* gat2_al = (const float*)d_in[15];
  const float* gat2_ar= (const float*)d_in[16]; const float* gat2_b = (const float*)d_in[17];
  const float* gat3_W = (const float*)d_in[18]; const float* gat3_al = (const float*)d_in[19];
  const float* gat3_ar= (const float*)d_in[20]; const float* gat3_b = (const float*)d_in[21];
  const float* fc1_W  = (const float*)d_in[22]; const float* fc1_b = (const float*)d_in[23];
  const float* fc2_W  = (const float*)d_in[24]; const float* fc2_b = (const float*)d_in[25];

  char* ws = (char*)d_ws;
  size_t off = 0;
  auto alloc = [&](size_t bytes) -> void* {
    void* p = ws + off;
    off += (bytes + 255) & ~(size_t)255;
    return p;
  };
  float* A       = (float*)alloc((size_t)NN * HH * 4);   // fp32 activations
  float* Bbuf    = (float*)alloc((size_t)NN * HH * 4);
  u16*   Zb      = (u16*)alloc((size_t)NN * ZW * 2);     // GAT z (bf16)
  u16*   Zagg_bf = (u16*)alloc((size_t)NN * HH * 2);     // gcn agg out (bf16)
  u16*   actb    = (u16*)alloc((size_t)NN * HH * 2);     // gcn activation (bf16) for next agg
  u16*   gbf     = (u16*)alloc((size_t)NN * HH * 2);     // gat activation (bf16)
  u16*   h_bf    = (u16*)alloc((size_t)NN * FIN * 2);
  int*   row_ptr = (int*)alloc((NN + 1) * 4);
  int*   csr_src = (int*)alloc((size_t)EE * 4);
  int*   meta    = (int*)alloc((size_t)3 * NN * 4);  // deg_src | deg_dst | fill
  int*   deg_src = meta;
  int*   deg_dst = meta + NN;
  int*   fill    = meta + 2 * NN;
  float* dsrc    = (float*)alloc(NN * 4);
  float* ddst    = (float*)alloc(NN * 4);
  int*   gstart  = (int*)alloc((GG + 1) * 4);
  float* asrc    = (float*)alloc(NN * 2 * 4);
  float* adst    = (float*)alloc(NN * 2 * 4);
  float* alpha   = (float*)alloc((size_t)EE * 2 * 4);
  float* wl      = (float*)alloc(2 * HH * 4);
  float* wr      = (float*)alloc(2 * HH * 4);
  float* partial = (float*)alloc((size_t)GG * RS * 2 * HH * 4);
  float* r1      = (float*)alloc(GG * 512 * 4);
  float* r2      = (float*)alloc(GG * 512 * 4);
  float* r3      = (float*)alloc(GG * 512 * 4);
  float* rg2     = (float*)alloc(GG * 512 * 4);
  float* rg3     = (float*)alloc(GG * 512 * 4);
  float* merged  = (float*)alloc(GG * 1024 * 4);
  u16* gcn1_Wt = (u16*)alloc((size_t)FIN * HH * 2);
  u16* gcn2_Wt = (u16*)alloc((size_t)HH * HH * 2);
  u16* gcn3_Wt = (u16*)alloc((size_t)HH * HH * 2);
  u16* gat1_Wt = (u16*)alloc((size_t)FIN * ZW * 2);
  u16* gat2_Wt = (u16*)alloc((size_t)HH * ZW * 2);
  u16* gat3_Wt = (u16*)alloc((size_t)HH * ZW * 2);

  const int MB = (NN + BM - 1) / BM;  // 79

  // preprocessing
  hipMemsetAsync(meta, 0, (size_t)3 * NN * 4, stream);
  count_deg_kernel<<<(EE + 255) / 256, 256, 0, stream>>>(src, dst, deg_src, deg_dst);
  norms_bounds_kernel<<<(NN + 255) / 256, 256, 0, stream>>>(deg_src, deg_dst, gid, dsrc, ddst, gstart);
  scan_kernel<<<1, 1024, 0, stream>>>(deg_dst, row_ptr);
  fill_csr_kernel<<<(EE + 255) / 256, 256, 0, stream>>>(src, dst, row_ptr, fill, csr_src);
  sort_rows_kernel<<<NN, 64, 0, stream>>>(row_ptr, csr_src);

  // weight converts
  transpose_bf16_kernel<<<(FIN * HH + 255) / 256, 256, 0, stream>>>(gcn1_W, gcn1_Wt, FIN, HH);
  transpose_bf16_kernel<<<(HH * HH + 255) / 256, 256, 0, stream>>>(gcn2_W, gcn2_Wt, HH, HH);
  transpose_bf16_kernel<<<(HH * HH + 255) / 256, 256, 0, stream>>>(gcn3_W, gcn3_Wt, HH, HH);
  transpose_bf16_kernel<<<(FIN * ZW + 255) / 256, 256, 0, stream>>>(gat1_W, gat1_Wt, FIN, ZW);
  transpose_bf16_kernel<<<(HH * ZW + 255) / 256, 256, 0, stream>>>(gat2_W, gat2_Wt, HH, ZW);
  transpose_bf16_kernel<<<(HH * ZW + 255) / 256, 256, 0, stream>>>(gat3_W, gat3_Wt, HH, ZW);
  convert_bf16_kernel<<<(NN * FIN + 255) / 256, 256, 0, stream>>>(h, h_bf, NN * FIN);

  // ---- GCN1 ----
  gcn_agg_kernel<<<(NN + 3) / 4, 256, 0, stream>>>(h_bf, dsrc, ddst, row_ptr, csr_src, Zagg_bf, FIN);
  gemm_mfma<<<dim3(MB, HH / BN), 256, 0, stream>>>(Zagg_bf, gcn1_Wt, gcn1_b, A, actb, NN, FIN, HH, 1);
  readout_stage1<<<dim3(GG, RS), HH, 0, stream>>>(A, gstart, partial);
  readout_stage2<<<GG, 512, 0, stream>>>(partial, gstart, r1);
  // ---- GCN2 ----
  gcn_agg_kernel<<<(NN + 3) / 4, 256, 0, stream>>>(actb, dsrc, ddst, row_ptr, csr_src, Zagg_bf, HH);
  gemm_mfma<<<dim3(MB, HH / BN), 256, 0, stream>>>(Zagg_bf, gcn2_Wt, gcn2_b, Bbuf, actb, NN, HH, HH, 1);
  readout_stage1<<<dim3(GG, RS), HH, 0, stream>>>(Bbuf, gstart, partial);
  readout_stage2<<<GG, 512, 0, stream>>>(partial, gstart, r2);
  // ---- GCN3 ----
  gcn_agg_kernel<<<(NN + 3) / 4, 256, 0, stream>>>(actb, dsrc, ddst, row_ptr, csr_src, Zagg_bf, HH);
  gemm_mfma<<<dim3(MB, HH / BN), 256, 0, stream>>>(Zagg_bf, gcn3_Wt, gcn3_b, A, nullptr, NN, HH, HH, 1);
  readout_stage1<<<dim3(GG, RS), HH, 0, stream>>>(A, gstart, partial);
  readout_stage2<<<GG, 512, 0, stream>>>(partial, gstart, r3);

  // ---- GAT1: input h (fp32 scores) / h_bf (gemm) ----
  gat_fold_kernel<<<(2 * FIN + 63) / 64, 64, 0, stream>>>(gat1_W, gat1_al, gat1_ar, wl, wr, FIN);
  gat_node_scores<<<NN, 64, 0, stream>>>(h, wl, wr, asrc, adst, FIN);
  gat_alpha_kernel<<<(NN * 2 + 255) / 256, 256, 0, stream>>>(asrc, adst, row_ptr, csr_src, alpha);
  gemm_mfma<<<dim3(MB, ZW / BN), 256, 0, stream>>>(h_bf, gat1_Wt, nullptr, nullptr, Zb, NN, FIN, ZW, 0);
  gat_agg_kernel<<<NN, 256, 0, stream>>>(Zb, alpha, gat1_b, row_ptr, csr_src, Bbuf, gbf);  // g1
  // ---- GAT2: input g1 (Bbuf / gbf) ----
  gat_fold_kernel<<<(2 * HH + 63) / 64, 64, 0, stream>>>(gat2_W, gat2_al, gat2_ar, wl, wr, HH);
  gat_node_scores<<<NN, 64, 0, stream>>>(Bbuf, wl, wr, asrc, adst, HH);
  gat_alpha_kernel<<<(NN * 2 + 255) / 256, 256, 0, stream>>>(asrc, adst, row_ptr, csr_src, alpha);
  gemm_mfma<<<dim3(MB, ZW / BN), 256, 0, stream>>>(gbf, gat2_Wt, nullptr, nullptr, Zb, NN, HH, ZW, 0);
  gat_agg_kernel<<<NN, 256, 0, stream>>>(Zb, alpha, gat2_b, row_ptr, csr_src, A, gbf);  // g2
  readout_stage1<<<dim3(GG, RS), HH, 0, stream>>>(A, gstart, partial);
  readout_stage2<<<GG, 512, 0, stream>>>(partial, gstart, rg2);
  // ---- GAT3: input g2 (A / gbf) ----
  gat_fold_kernel<<<(2 * HH + 63) / 64, 64, 0, stream>>>(gat3_W, gat3_al, gat3_ar, wl, wr, HH);
  gat_node_scores<<<NN, 64, 0, stream>>>(A, wl, wr, asrc, adst, HH);
  gat_alpha_kernel<<<(NN * 2 + 255) / 256, 256, 0, stream>>>(asrc, adst, row_ptr, csr_src, alpha);
  gemm_mfma<<<dim3(MB, ZW / BN), 256, 0, stream>>>(gbf, gat3_Wt, nullptr, nullptr, Zb, NN, HH, ZW, 0);
  gat_agg_kernel<<<NN, 256, 0, stream>>>(Zb, alpha, gat3_b, row_ptr, csr_src, Bbuf, gbf);  // g3
  readout_stage1<<<dim3(GG, RS), HH, 0, stream>>>(Bbuf, gstart, partial);
  readout_stage2<<<GG, 512, 0, stream>>>(partial, gstart, rg3);

  // merge + FC head
  assemble_kernel<<<(GG * 512 + 255) / 256, 256, 0, stream>>>(r1, r2, r3, rg2, rg3, merged);
  fc_head_kernel<<<GG, 128, 0, stream>>>(merged, fc1_W, fc1_b, fc2_W, fc2_b, (float*)d_out);
}

// Round 4
// 366.016 us; speedup vs baseline: 2.7845x; 1.5032x over previous
//
#include <hip/hip_runtime.h>
#include <math.h>

#define NN 10000
#define EE 160000
#define GG 64
#define FIN 128
#define HH 256
#define ZW 512 /* HEADS*H */
#define RS 8   /* readout slices per graph */

typedef unsigned short u16;
using bf16x8 = __attribute__((ext_vector_type(8))) short;
using f32x4 = __attribute__((ext_vector_type(4))) float;

__device__ inline u16 f2bf(float x) {
  union { float f; unsigned u; } v; v.f = x;
  unsigned r = v.u + 0x7FFF + ((v.u >> 16) & 1);
  return (u16)(r >> 16);
}
__device__ inline float bf2f(u16 x) {
  union { unsigned u; float f; } v; v.u = ((unsigned)x) << 16; return v.f;
}
__device__ inline float bflo(unsigned pair) {
  union { unsigned u; float f; } v; v.u = pair << 16; return v.f;
}
__device__ inline float bfhi(unsigned pair) {
  union { unsigned u; float f; } v; v.u = pair & 0xFFFF0000u; return v.f;
}

// ---------------- graph preprocessing ----------------

__global__ void count_deg_kernel(const int* __restrict__ src, const int* __restrict__ dst,
                                 int* deg_src, int* deg_dst) {
  int e = blockIdx.x * blockDim.x + threadIdx.x;
  if (e < EE) {
    atomicAdd(&deg_src[src[e]], 1);
    atomicAdd(&deg_dst[dst[e]], 1);
  }
}

__global__ void norms_bounds_kernel(const int* __restrict__ deg_src, const int* __restrict__ deg_dst,
                                    const int* __restrict__ gid,
                                    float* dsrc, float* ddst, int* gstart) {
  int n = blockIdx.x * blockDim.x + threadIdx.x;
  if (n < NN) {
    int a = deg_src[n]; if (a < 1) a = 1;
    int b = deg_dst[n]; if (b < 1) b = 1;
    dsrc[n] = 1.0f / sqrtf((float)a);
    ddst[n] = 1.0f / sqrtf((float)b);
    if (n == 0) gstart[gid[0]] = 0;
    else if (gid[n] != gid[n - 1]) gstart[gid[n]] = n;
    if (n == NN - 1) gstart[GG] = NN;
  }
}

// exclusive scan of deg_dst -> row_ptr[0..NN]  (single block, 1024 threads, shfl scans)
__global__ __launch_bounds__(1024) void scan_kernel(const int* __restrict__ deg, int* row_ptr) {
  __shared__ int wsum[16];
  __shared__ int carry;
  int lane = threadIdx.x & 63, wid = threadIdx.x >> 6;
  if (threadIdx.x == 0) { carry = 0; row_ptr[0] = 0; }
  __syncthreads();
  for (int base = 0; base < NN; base += 1024) {
    int i = base + threadIdx.x;
    int x = (i < NN) ? deg[i] : 0;
#pragma unroll
    for (int off = 1; off < 64; off <<= 1) {
      int t = __shfl_up(x, off);
      if (lane >= off) x += t;
    }
    if (lane == 63) wsum[wid] = x;
    __syncthreads();
    if (wid == 0 && lane < 16) {
      int y = wsum[lane];
#pragma unroll
      for (int off = 1; off < 16; off <<= 1) {
        int t = __shfl_up(y, off, 16);
        if (lane >= off) y += t;
      }
      wsum[lane] = y;
    }
    __syncthreads();
    int woff = (wid > 0) ? wsum[wid - 1] : 0;
    if (i < NN) row_ptr[i + 1] = carry + woff + x;
    int total = wsum[15];
    __syncthreads();
    if (threadIdx.x == 0) carry += total;
    __syncthreads();
  }
}

__global__ void fill_csr_kernel(const int* __restrict__ src, const int* __restrict__ dst,
                                const int* __restrict__ row_ptr, int* fill, int* csr_src) {
  int e = blockIdx.x * blockDim.x + threadIdx.x;
  if (e < EE) {
    int d = dst[e];
    int p = atomicAdd(&fill[d], 1);
    csr_src[row_ptr[d] + p] = src[e];
  }
}

// deterministic row order: parallel rank-sort, one 64-thread block per row
__global__ __launch_bounds__(64) void sort_rows_kernel(const int* __restrict__ row_ptr,
                                                       int* csr_src) {
  int n = blockIdx.x;
  int s0 = row_ptr[n];
  int L = row_ptr[n + 1] - s0;
  if (L <= 1) return;
  __shared__ int buf[512];
  if (L <= 512) {
    for (int i = threadIdx.x; i < L; i += 64) buf[i] = csr_src[s0 + i];
    __syncthreads();
    for (int i = threadIdx.x; i < L; i += 64) {
      int v = buf[i], r = 0;
      for (int j = 0; j < L; j++) {
        int u = buf[j];
        r += (u < v) || (u == v && j < i);
      }
      csr_src[s0 + r] = v;
    }
  } else if (threadIdx.x == 0) {
    for (int i = s0 + 1; i < s0 + L; i++) {
      int v = csr_src[i], j = i - 1;
      while (j >= s0 && csr_src[j] > v) { csr_src[j + 1] = csr_src[j]; j--; }
      csr_src[j + 1] = v;
    }
  }
}

// ---------------- prep mega-kernel: 6 transposes + h->bf16 + 3 folds ----------------
// block ranges: [0,128) gcn1T, [128,384) gcn2T, [384,640) gcn3T, [640,896) gat1T,
// [896,1408) gat2T, [1408,1920) gat3T, [1920,3170) conv h, [3170,3175) folds
__global__ __launch_bounds__(256) void prep_kernel(
    const float* __restrict__ gcn1_W, u16* __restrict__ gcn1_Wt,
    const float* __restrict__ gcn2_W, u16* __restrict__ gcn2_Wt,
    const float* __restrict__ gcn3_W, u16* __restrict__ gcn3_Wt,
    const float* __restrict__ gat1_W, u16* __restrict__ gat1_Wt,
    const float* __restrict__ gat2_W, u16* __restrict__ gat2_Wt,
    const float* __restrict__ gat3_W, u16* __restrict__ gat3_Wt,
    const float* __restrict__ h, u16* __restrict__ h_bf,
    const float* __restrict__ al1, const float* __restrict__ ar1,
    const float* __restrict__ al2, const float* __restrict__ ar2,
    const float* __restrict__ al3, const float* __restrict__ ar3,
    float* __restrict__ wl1, float* __restrict__ wr1,
    float* __restrict__ wl2, float* __restrict__ wr2,
    float* __restrict__ wl3, float* __restrict__ wr3) {
  int b = blockIdx.x, t = threadIdx.x;
  if (b < 1920) {
    const float* W; u16* Wt; int K, N, idx;
    if (b < 128)       { W = gcn1_W; Wt = gcn1_Wt; K = 128; N = 256; idx = b * 256 + t; }
    else if (b < 384)  { W = gcn2_W; Wt = gcn2_Wt; K = 256; N = 256; idx = (b - 128) * 256 + t; }
    else if (b < 640)  { W = gcn3_W; Wt = gcn3_Wt; K = 256; N = 256; idx = (b - 384) * 256 + t; }
    else if (b < 896)  { W = gat1_W; Wt = gat1_Wt; K = 128; N = 512; idx = (b - 640) * 256 + t; }
    else if (b < 1408) { W = gat2_W; Wt = gat2_Wt; K = 256; N = 512; idx = (b - 896) * 256 + t; }
    else               { W = gat3_W; Wt = gat3_Wt; K = 256; N = 512; idx = (b - 1408) * 256 + t; }
    int k = idx / N, n = idx - k * N;
    Wt[(size_t)n * K + k] = f2bf(W[idx]);
  } else if (b < 3170) {
    int idx = (b - 1920) * 256 + t;
    float4 v = *(const float4*)&h[(size_t)idx * 4];
    ushort4 o;
    o.x = f2bf(v.x); o.y = f2bf(v.y); o.z = f2bf(v.z); o.w = f2bf(v.w);
    *(ushort4*)&h_bf[(size_t)idx * 4] = o;
  } else {
    int jb = b - 3170;
    const float* W; const float* al; const float* ar; float* wl; float* wr; int K, i;
    if (jb == 0)      { W = gat1_W; al = al1; ar = ar1; wl = wl1; wr = wr1; K = 128; i = t; }
    else if (jb <= 2) { W = gat2_W; al = al2; ar = ar2; wl = wl2; wr = wr2; K = 256; i = (jb - 1) * 256 + t; }
    else              { W = gat3_W; al = al3; ar = ar3; wl = wl3; wr = wr3; K = 256; i = (jb - 3) * 256 + t; }
    int hh = i / K, k = i - hh * K;
    float sl = 0.f, sr = 0.f;
    for (int f = 0; f < HH; f++) {
      float wv = W[(size_t)k * ZW + hh * HH + f];
      sl += wv * al[hh * HH + f];
      sr += wv * ar[hh * HH + f];
    }
    wl[hh * K + k] = sl;
    wr[hh * K + k] = sr;
  }
}

// ---------------- GCN aggregate (bf16 in/out, wave per node, 2x unroll) ----------------
__global__ __launch_bounds__(256) void gcn_agg_kernel(
    const u16* __restrict__ xb, const float* __restrict__ dsrc, const float* __restrict__ ddst,
    const int* __restrict__ row_ptr, const int* __restrict__ csr_src,
    u16* __restrict__ out, int F) {
  int wid = threadIdx.x >> 6, lane = threadIdx.x & 63;
  int n = blockIdx.x * 4 + wid;
  if (n >= NN) return;
  int s0 = row_ptr[n], s1 = row_ptr[n + 1];
  float dd = ddst[n];
  if (F == 256) {
    int bf = lane * 4;
    float a0 = 0, a1 = 0, a2 = 0, a3 = 0;
    int e = s0;
    for (; e + 1 < s1; e += 2) {
      int sA = csr_src[e], sB = csr_src[e + 1];
      float wA = dsrc[sA], wB = dsrc[sB];
      uint2 vA = *(const uint2*)&xb[(size_t)sA * 256 + bf];
      uint2 vB = *(const uint2*)&xb[(size_t)sB * 256 + bf];
      a0 += wA * bflo(vA.x) + wB * bflo(vB.x);
      a1 += wA * bfhi(vA.x) + wB * bfhi(vB.x);
      a2 += wA * bflo(vA.y) + wB * bflo(vB.y);
      a3 += wA * bfhi(vA.y) + wB * bfhi(vB.y);
    }
    if (e < s1) {
      int s = csr_src[e];
      float w = dsrc[s];
      uint2 v = *(const uint2*)&xb[(size_t)s * 256 + bf];
      a0 += w * bflo(v.x); a1 += w * bfhi(v.x);
      a2 += w * bflo(v.y); a3 += w * bfhi(v.y);
    }
    ushort4 o;
    o.x = f2bf(a0 * dd); o.y = f2bf(a1 * dd); o.z = f2bf(a2 * dd); o.w = f2bf(a3 * dd);
    *(ushort4*)&out[(size_t)n * 256 + bf] = o;
  } else {  // F == 128
    int bf = lane * 2;
    float a0 = 0, a1 = 0;
    int e = s0;
    for (; e + 1 < s1; e += 2) {
      int sA = csr_src[e], sB = csr_src[e + 1];
      float wA = dsrc[sA], wB = dsrc[sB];
      unsigned vA = *(const unsigned*)&xb[(size_t)sA * 128 + bf];
      unsigned vB = *(const unsigned*)&xb[(size_t)sB * 128 + bf];
      a0 += wA * bflo(vA) + wB * bflo(vB);
      a1 += wA * bfhi(vA) + wB * bfhi(vB);
    }
    if (e < s1) {
      int s = csr_src[e];
      float w = dsrc[s];
      unsigned v = *(const unsigned*)&xb[(size_t)s * 128 + bf];
      a0 += w * bflo(v); a1 += w * bfhi(v);
    }
    ushort2 o;
    o.x = f2bf(a0 * dd); o.y = f2bf(a1 * dd);
    *(ushort2*)&out[(size_t)n * 128 + bf] = o;
  }
}

// ---------------- bf16 MFMA GEMM: act(A[M,K] @ Wt[Nc,K]^T + bias) -> bf16 Cb ----------------
#define BM 128
#define BN 64
#define BK 64
#define LPAD 8
__global__ __launch_bounds__(256) void gemm_mfma(
    const u16* __restrict__ A, const u16* __restrict__ Wt,
    const float* __restrict__ bias, u16* __restrict__ Cb,
    int M, int K, int Nc, int relu) {
  __shared__ u16 As[BM][BK + LPAD];
  __shared__ u16 Bs[BN][BK + LPAD];
  int tid = threadIdx.x;
  int lane = tid & 63;
  int wid = tid >> 6;
  int wm = wid & 1, wn = wid >> 1;
  int l15 = lane & 15, lg = lane >> 4;
  int row0 = blockIdx.x * BM;
  int col0 = blockIdx.y * BN;
  f32x4 acc[4][2] = {};
  for (int k0 = 0; k0 < K; k0 += BK) {
#pragma unroll
    for (int p = 0; p < 4; p++) {
      int c = p * 256 + tid;
      int r = c >> 3, k8 = c & 7;
      uint4 v = make_uint4(0, 0, 0, 0);
      int gr = row0 + r;
      if (gr < M) v = *(const uint4*)&A[(size_t)gr * K + k0 + k8 * 8];
      *(uint4*)&As[r][k8 * 8] = v;
    }
#pragma unroll
    for (int p = 0; p < 2; p++) {
      int c = p * 256 + tid;
      int r = c >> 3, k8 = c & 7;
      uint4 v = *(const uint4*)&Wt[(size_t)(col0 + r) * K + k0 + k8 * 8];
      *(uint4*)&Bs[r][k8 * 8] = v;
    }
    __syncthreads();
#pragma unroll
    for (int ks = 0; ks < BK; ks += 32) {
      bf16x8 afr[4], bfr[2];
#pragma unroll
      for (int m = 0; m < 4; m++)
        afr[m] = *(const bf16x8*)&As[wm * 64 + m * 16 + l15][ks + lg * 8];
#pragma unroll
      for (int n = 0; n < 2; n++)
        bfr[n] = *(const bf16x8*)&Bs[wn * 32 + n * 16 + l15][ks + lg * 8];
#pragma unroll
      for (int m = 0; m < 4; m++)
#pragma unroll
        for (int n = 0; n < 2; n++)
          acc[m][n] = __builtin_amdgcn_mfma_f32_16x16x32_bf16(afr[m], bfr[n], acc[m][n], 0, 0, 0);
    }
    __syncthreads();
  }
#pragma unroll
  for (int m = 0; m < 4; m++) {
#pragma unroll
    for (int n = 0; n < 2; n++) {
      int gc = col0 + wn * 32 + n * 16 + l15;
      float bv = bias ? bias[gc] : 0.f;
#pragma unroll
      for (int j = 0; j < 4; j++) {
        int gr = row0 + wm * 64 + m * 16 + lg * 4 + j;
        if (gr < M) {
          float v = acc[m][n][j] + bv;
          if (relu) v = fmaxf(v, 0.f);
          Cb[(size_t)gr * Nc + gc] = f2bf(v);
        }
      }
    }
  }
}

// ---------------- GAT node scores from fp32 x (first layer only) ----------------
__global__ __launch_bounds__(64) void gat_node_scores(const float* __restrict__ x,
                                                      const float* __restrict__ wl,
                                                      const float* __restrict__ wr,
                                                      float* __restrict__ asrc,
                                                      float* __restrict__ adst, int K) {
  int n = blockIdx.x, lane = threadIdx.x;
  float a0 = 0, a1 = 0, b0 = 0, b1 = 0;
  for (int k = lane; k < K; k += 64) {
    float xv = x[(size_t)n * K + k];
    a0 += xv * wl[k];
    a1 += xv * wl[K + k];
    b0 += xv * wr[k];
    b1 += xv * wr[K + k];
  }
  for (int off = 32; off; off >>= 1) {
    a0 += __shfl_down(a0, off);
    a1 += __shfl_down(a1, off);
    b0 += __shfl_down(b0, off);
    b1 += __shfl_down(b1, off);
  }
  if (lane == 0) {
    asrc[n * 2 + 0] = a0; asrc[n * 2 + 1] = a1;
    adst[n * 2 + 0] = b0; adst[n * 2 + 1] = b1;
  }
}

// ---------------- per-edge softmax weights alpha[e][h], wave per node ----------------
__global__ __launch_bounds__(64) void gat_alpha_kernel(
    const float* __restrict__ asrc, const float* __restrict__ adst,
    const int* __restrict__ row_ptr, const int* __restrict__ csr_src,
    float* __restrict__ alpha) {
  int n = blockIdx.x, lane = threadIdx.x;
  int s0 = row_ptr[n], s1 = row_ptr[n + 1];
  if (s1 <= s0) return;
  float2 an = *(const float2*)&adst[n * 2];
  float m0 = -INFINITY, m1 = -INFINITY;
  for (int e = s0 + lane; e < s1; e += 64) {
    float2 as = *(const float2*)&asrc[csr_src[e] * 2];
    float e0 = as.x + an.x; e0 = (e0 > 0.f) ? e0 : 0.2f * e0;
    float e1 = as.y + an.y; e1 = (e1 > 0.f) ? e1 : 0.2f * e1;
    m0 = fmaxf(m0, e0); m1 = fmaxf(m1, e1);
  }
#pragma unroll
  for (int off = 32; off; off >>= 1) {
    m0 = fmaxf(m0, __shfl_xor(m0, off));
    m1 = fmaxf(m1, __shfl_xor(m1, off));
  }
  float s0f = 0.f, s1f = 0.f;
  for (int e = s0 + lane; e < s1; e += 64) {
    float2 as = *(const float2*)&asrc[csr_src[e] * 2];
    float e0 = as.x + an.x; e0 = (e0 > 0.f) ? e0 : 0.2f * e0;
    float e1 = as.y + an.y; e1 = (e1 > 0.f) ? e1 : 0.2f * e1;
    s0f += __expf(e0 - m0); s1f += __expf(e1 - m1);
  }
#pragma unroll
  for (int off = 32; off; off >>= 1) {
    s0f += __shfl_xor(s0f, off);
    s1f += __shfl_xor(s1f, off);
  }
  float i0 = (s0f > 0.f) ? 1.f / s0f : 0.f;
  float i1 = (s1f > 0.f) ? 1.f / s1f : 0.f;
  for (int e = s0 + lane; e < s1; e += 64) {
    float2 as = *(const float2*)&asrc[csr_src[e] * 2];
    float e0 = as.x + an.x; e0 = (e0 > 0.f) ? e0 : 0.2f * e0;
    float e1 = as.y + an.y; e1 = (e1 > 0.f) ? e1 : 0.2f * e1;
    float2 o; o.x = __expf(e0 - m0) * i0; o.y = __expf(e1 - m1) * i1;
    *(float2*)&alpha[e * 2] = o;
  }
}

// ---------------- GAT aggregate + relu + head-mean + (fused next-layer scores) ----------------
__global__ __launch_bounds__(256) void gat_agg_kernel(
    const u16* __restrict__ zb, const float* __restrict__ alpha, const float* __restrict__ b,
    const int* __restrict__ row_ptr, const int* __restrict__ csr_src,
    u16* __restrict__ out_bf,
    const float* __restrict__ wlN, const float* __restrict__ wrN,
    float* __restrict__ asrcN, float* __restrict__ adstN) {
  int n = blockIdx.x;
  int tid = threadIdx.x;
  int h = tid >> 7;       // 0..1
  int p = tid & 127;      // bf16-pair index: features 2p, 2p+1 of head h
  int s0 = row_ptr[n], s1 = row_ptr[n + 1];
  float a0 = 0.f, a1 = 0.f;
  int e = s0;
  for (; e + 1 < s1; e += 2) {
    int sA = csr_src[e], sB = csr_src[e + 1];
    float wA = alpha[e * 2 + h], wB = alpha[(e + 1) * 2 + h];
    unsigned zA = *(const unsigned*)&zb[(size_t)sA * ZW + h * HH + p * 2];
    unsigned zB = *(const unsigned*)&zb[(size_t)sB * ZW + h * HH + p * 2];
    a0 += wA * bflo(zA) + wB * bflo(zB);
    a1 += wA * bfhi(zA) + wB * bfhi(zB);
  }
  if (e < s1) {
    int s = csr_src[e];
    float w = alpha[e * 2 + h];
    unsigned zv = *(const unsigned*)&zb[(size_t)s * ZW + h * HH + p * 2];
    a0 += w * bflo(zv);
    a1 += w * bfhi(zv);
  }
  float r0 = fmaxf(a0 + b[h * HH + p * 2 + 0], 0.f);
  float r1 = fmaxf(a1 + b[h * HH + p * 2 + 1], 0.f);
  __shared__ float hv[2][HH];
  hv[h][p * 2 + 0] = r0;
  hv[h][p * 2 + 1] = r1;
  __syncthreads();
  float o = 0.5f * (hv[0][tid] + hv[1][tid]);
  out_bf[(size_t)n * HH + tid] = f2bf(o);
  if (wlN) {
    // next-layer node scores: asrcN[n][h'] = sum_t o_t * wlN[h'*256+t], same for adstN
    float p0 = o * wlN[tid], p1 = o * wlN[256 + tid];
    float q0 = o * wrN[tid], q1 = o * wrN[256 + tid];
    int lane = tid & 63, wid = tid >> 6;
#pragma unroll
    for (int off = 32; off; off >>= 1) {
      p0 += __shfl_down(p0, off);
      p1 += __shfl_down(p1, off);
      q0 += __shfl_down(q0, off);
      q1 += __shfl_down(q1, off);
    }
    __shared__ float red[4][4];
    if (lane == 0) { red[wid][0] = p0; red[wid][1] = p1; red[wid][2] = q0; red[wid][3] = q1; }
    __syncthreads();
    if (tid == 0) {
      asrcN[n * 2 + 0] = red[0][0] + red[1][0] + red[2][0] + red[3][0];
      asrcN[n * 2 + 1] = red[0][1] + red[1][1] + red[2][1] + red[3][1];
      adstN[n * 2 + 0] = red[0][2] + red[1][2] + red[2][2] + red[3][2];
      adstN[n * 2 + 1] = red[0][3] + red[1][3] + red[2][3] + red[3][3];
    }
  }
}

// ---------------- batched two-stage readout over 5 bf16 activations ----------------
struct ActPtrs { const u16* a[5]; };

__global__ __launch_bounds__(256) void readout_stage1(ActPtrs acts,
                                                      const int* __restrict__ gstart,
                                                      float* __restrict__ partial) {
  int g = blockIdx.x, s = blockIdx.y, l = blockIdx.z, f = threadIdx.x;
  const u16* x = acts.a[l];
  int n0 = gstart[g], n1 = gstart[g + 1];
  int cnt = n1 - n0;
  int chunk = (cnt + RS - 1) / RS;
  int a = n0 + s * chunk;
  int bnd = a + chunk; if (bnd > n1) bnd = n1;
  float sum = 0.f, mx = -INFINITY;
  for (int n = a; n < bnd; n++) {
    float v = bf2f(x[(size_t)n * HH + f]);
    sum += v;
    mx = fmaxf(mx, v);
  }
  size_t base = ((size_t)l * GG * RS + g * RS + s) * 2 * HH;
  partial[base + f] = sum;
  partial[base + HH + f] = mx;
}

__global__ __launch_bounds__(512) void readout_stage2(const float* __restrict__ partial,
                                                      const int* __restrict__ gstart,
                                                      float* __restrict__ rr) {
  int g = blockIdx.x, l = blockIdx.y, t = threadIdx.x;
  int f = t & 255, ismax = t >> 8;
  size_t base = ((size_t)l * GG * RS + g * RS) * 2 * HH;
  if (!ismax) {
    float s = 0.f;
    for (int k = 0; k < RS; k++) s += partial[base + (size_t)k * 2 * HH + f];
    rr[(size_t)l * GG * 512 + g * 512 + f] = s / (float)(gstart[g + 1] - gstart[g]);
  } else {
    float m = -INFINITY;
    for (int k = 0; k < RS; k++) m = fmaxf(m, partial[base + (size_t)k * 2 * HH + HH + f]);
    rr[(size_t)l * GG * 512 + g * 512 + 256 + f] = m;
  }
}

// ---------------- FC head with assemble fused ----------------
// rr layers: 0=gcn1, 1=gcn2, 2=gcn3, 3=g2, 4=g3
__global__ __launch_bounds__(128) void fc_head_kernel(
    const float* __restrict__ rr, const float* __restrict__ W1, const float* __restrict__ b1,
    const float* __restrict__ W2, const float* __restrict__ b2, float* __restrict__ out) {
  int g = blockIdx.x;
  int t = threadIdx.x;
  __shared__ float row[1024];
  __shared__ float f1[128];
  const float* R0 = rr + 0 * GG * 512 + g * 512;
  const float* R1 = rr + 1 * GG * 512 + g * 512;
  const float* R2 = rr + 2 * GG * 512 + g * 512;
  const float* R3 = rr + 3 * GG * 512 + g * 512;
  const float* R4 = rr + 4 * GG * 512 + g * 512;
  for (int c = t; c < 512; c += 128) {
    float spec = R0[c] + R1[c] + R2[c];
    float s3 = (c < 256) ? R3[c] : R4[c];
    float spat = R0[c] + R3[c] + s3;
    row[c] = spec;
    row[512 + c] = spat;
  }
  __syncthreads();
  float acc = b1[t];
  for (int k = 0; k < 1024; k++) acc += row[k] * W1[k * 128 + t];
  f1[t] = fmaxf(acc, 0.f);
  __syncthreads();
  if (t < 2) {
    float a = b2[t];
    for (int k = 0; k < 128; k++) a += f1[k] * W2[k * 2 + t];
    out[g * 2 + t] = 1.f / (1.f + expf(-a));
  }
}

extern "C" void kernel_launch(void* const* d_in, const int* in_sizes, int n_in,
                              void* d_out, int out_size, void* d_ws, size_t ws_size,
                              hipStream_t stream) {
  const float* h      = (const float*)d_in[0];
  const int*   src    = (const int*)d_in[1];
  const int*   dst    = (const int*)d_in[2];
  const int*   gid    = (const int*)d_in[3];
  const float* gcn1_W = (const float*)d_in[4];  const float* gcn1_b = (const float*)d_in[5];
  const float* gcn2_W = (const float*)d_in[6];  const float* gcn2_b = (const float*)d_in[7];
  const float* gcn3_W = (const float*)d_in[8];  const float* gcn3_b = (const float*)d_in[9];
  const float* gat1_W = (const float*)d_in[10]; const float* gat1_al = (const float*)d_in[11];
  const float* gat1_ar= (const float*)d_in[12]; const float* gat1_b = (const float*)d_in[13];
  const float* gat2_W = (const float*)d_in[14]; const float* gat2_al = (const float*)d_in[15];
  const float* gat2_ar= (const float*)d_in[16]; const float* gat2_b = (const float*)d_in[17];
  const float* gat3_W = (const float*)d_in[18]; const float* gat3_al = (const float*)d_in[19];
  const float* gat3_ar= (const float*)d_in[20]; const float* gat3_b = (const float*)d_in[21];
  const float* fc1_W  = (const float*)d_in[22]; const float* fc1_b = (const float*)d_in[23];
  const float* fc2_W  = (const float*)d_in[24]; const float* fc2_b = (const float*)d_in[25];

  char* ws = (char*)d_ws;
  size_t off = 0;
  auto alloc = [&](size_t bytes) -> void* {
    void* p = ws + off;
    off += (bytes + 255) & ~(size_t)255;
    return p;
  };
  u16*   Zb      = (u16*)alloc((size_t)NN * ZW * 2);     // GAT z (bf16)
  u16*   Zagg_bf = (u16*)alloc((size_t)NN * HH * 2);     // gcn agg out (bf16)
  u16*   h_bf    = (u16*)alloc((size_t)NN * FIN * 2);
  u16*   ab1     = (u16*)alloc((size_t)NN * HH * 2);     // gcn1 act
  u16*   ab2     = (u16*)alloc((size_t)NN * HH * 2);
  u16*   ab3     = (u16*)alloc((size_t)NN * HH * 2);
  u16*   gb1     = (u16*)alloc((size_t)NN * HH * 2);     // gat1 act
  u16*   gb2     = (u16*)alloc((size_t)NN * HH * 2);
  u16*   gb3     = (u16*)alloc((size_t)NN * HH * 2);
  int*   row_ptr = (int*)alloc((NN + 1) * 4);
  int*   csr_src = (int*)alloc((size_t)EE * 4);
  int*   meta    = (int*)alloc((size_t)3 * NN * 4);  // deg_src | deg_dst | fill
  int*   deg_src = meta;
  int*   deg_dst = meta + NN;
  int*   fill    = meta + 2 * NN;
  float* dsrc    = (float*)alloc(NN * 4);
  float* ddst    = (float*)alloc(NN * 4);
  int*   gstart  = (int*)alloc((GG + 1) * 4);
  float* asrc    = (float*)alloc(NN * 2 * 4);
  float* adst    = (float*)alloc(NN * 2 * 4);
  float* alpha   = (float*)alloc((size_t)EE * 2 * 4);
  float* wl1     = (float*)alloc(2 * FIN * 4);
  float* wr1     = (float*)alloc(2 * FIN * 4);
  float* wl2     = (float*)alloc(2 * HH * 4);
  float* wr2     = (float*)alloc(2 * HH * 4);
  float* wl3     = (float*)alloc(2 * HH * 4);
  float* wr3     = (float*)alloc(2 * HH * 4);
  float* partial = (float*)alloc((size_t)5 * GG * RS * 2 * HH * 4);
  float* rr      = (float*)alloc((size_t)5 * GG * 512 * 4);
  u16* gcn1_Wt = (u16*)alloc((size_t)FIN * HH * 2);
  u16* gcn2_Wt = (u16*)alloc((size_t)HH * HH * 2);
  u16* gcn3_Wt = (u16*)alloc((size_t)HH * HH * 2);
  u16* gat1_Wt = (u16*)alloc((size_t)FIN * ZW * 2);
  u16* gat2_Wt = (u16*)alloc((size_t)HH * ZW * 2);
  u16* gat3_Wt = (u16*)alloc((size_t)HH * ZW * 2);

  const int MB = (NN + BM - 1) / BM;  // 79

  // preprocessing
  hipMemsetAsync(meta, 0, (size_t)3 * NN * 4, stream);
  count_deg_kernel<<<(EE + 255) / 256, 256, 0, stream>>>(src, dst, deg_src, deg_dst);
  norms_bounds_kernel<<<(NN + 255) / 256, 256, 0, stream>>>(deg_src, deg_dst, gid, dsrc, ddst, gstart);
  scan_kernel<<<1, 1024, 0, stream>>>(deg_dst, row_ptr);
  fill_csr_kernel<<<(EE + 255) / 256, 256, 0, stream>>>(src, dst, row_ptr, fill, csr_src);
  sort_rows_kernel<<<NN, 64, 0, stream>>>(row_ptr, csr_src);

  prep_kernel<<<3175, 256, 0, stream>>>(
      gcn1_W, gcn1_Wt, gcn2_W, gcn2_Wt, gcn3_W, gcn3_Wt,
      gat1_W, gat1_Wt, gat2_W, gat2_Wt, gat3_W, gat3_Wt,
      h, h_bf,
      gat1_al, gat1_ar, gat2_al, gat2_ar, gat3_al, gat3_ar,
      wl1, wr1, wl2, wr2, wl3, wr3);

  // ---- GCN chain ----
  gcn_agg_kernel<<<(NN + 3) / 4, 256, 0, stream>>>(h_bf, dsrc, ddst, row_ptr, csr_src, Zagg_bf, FIN);
  gemm_mfma<<<dim3(MB, HH / BN), 256, 0, stream>>>(Zagg_bf, gcn1_Wt, gcn1_b, ab1, NN, FIN, HH, 1);
  gcn_agg_kernel<<<(NN + 3) / 4, 256, 0, stream>>>(ab1, dsrc, ddst, row_ptr, csr_src, Zagg_bf, HH);
  gemm_mfma<<<dim3(MB, HH / BN), 256, 0, stream>>>(Zagg_bf, gcn2_Wt, gcn2_b, ab2, NN, HH, HH, 1);
  gcn_agg_kernel<<<(NN + 3) / 4, 256, 0, stream>>>(ab2, dsrc, ddst, row_ptr, csr_src, Zagg_bf, HH);
  gemm_mfma<<<dim3(MB, HH / BN), 256, 0, stream>>>(Zagg_bf, gcn3_Wt, gcn3_b, ab3, NN, HH, HH, 1);

  // ---- GAT1 ----
  gat_node_scores<<<NN, 64, 0, stream>>>(h, wl1, wr1, asrc, adst, FIN);
  gat_alpha_kernel<<<NN, 64, 0, stream>>>(asrc, adst, row_ptr, csr_src, alpha);
  gemm_mfma<<<dim3(MB, ZW / BN), 256, 0, stream>>>(h_bf, gat1_Wt, nullptr, Zb, NN, FIN, ZW, 0);
  gat_agg_kernel<<<NN, 256, 0, stream>>>(Zb, alpha, gat1_b, row_ptr, csr_src, gb1,
                                         wl2, wr2, asrc, adst);  // fused scores for GAT2
  // ---- GAT2 ----
  gat_alpha_kernel<<<NN, 64, 0, stream>>>(asrc, adst, row_ptr, csr_src, alpha);
  gemm_mfma<<<dim3(MB, ZW / BN), 256, 0, stream>>>(gb1, gat2_Wt, nullptr, Zb, NN, HH, ZW, 0);
  gat_agg_kernel<<<NN, 256, 0, stream>>>(Zb, alpha, gat2_b, row_ptr, csr_src, gb2,
                                         wl3, wr3, asrc, adst);  // fused scores for GAT3
  // ---- GAT3 ----
  gat_alpha_kernel<<<NN, 64, 0, stream>>>(asrc, adst, row_ptr, csr_src, alpha);
  gemm_mfma<<<dim3(MB, ZW / BN), 256, 0, stream>>>(gb2, gat3_Wt, nullptr, Zb, NN, HH, ZW, 0);
  gat_agg_kernel<<<NN, 256, 0, stream>>>(Zb, alpha, gat3_b, row_ptr, csr_src, gb3,
                                         nullptr, nullptr, nullptr, nullptr);

  // ---- batched readouts over {ab1, ab2, ab3, gb2, gb3} ----
  ActPtrs acts;
  acts.a[0] = ab1; acts.a[1] = ab2; acts.a[2] = ab3; acts.a[3] = gb2; acts.a[4] = gb3;
  readout_stage1<<<dim3(GG, RS, 5), 256, 0, stream>>>(acts, gstart, partial);
  readout_stage2<<<dim3(GG, 5), 512, 0, stream>>>(partial, gstart, rr);

  // ---- FC head (assemble fused) ----
  fc_head_kernel<<<GG, 128, 0, stream>>>(rr, fc1_W, fc1_b, fc2_W, fc2_b, (float*)d_out);
}

// Round 5
// 295.888 us; speedup vs baseline: 3.4445x; 1.2370x over previous
//
#include <hip/hip_runtime.h>
#include <math.h>

#define NN 10000
#define EE 160000
#define GG 64
#define FIN 128
#define HH 256
#define ZW 512 /* HEADS*H */
#define RS 8   /* readout slices per graph */

typedef unsigned short u16;
using bf16x8 = __attribute__((ext_vector_type(8))) short;
using f32x4 = __attribute__((ext_vector_type(4))) float;

__device__ inline u16 f2bf(float x) {
  union { float f; unsigned u; } v; v.f = x;
  unsigned r = v.u + 0x7FFF + ((v.u >> 16) & 1);
  return (u16)(r >> 16);
}
__device__ inline float bf2f(u16 x) {
  union { unsigned u; float f; } v; v.u = ((unsigned)x) << 16; return v.f;
}
__device__ inline float bflo(unsigned pair) {
  union { unsigned u; float f; } v; v.u = pair << 16; return v.f;
}
__device__ inline float bfhi(unsigned pair) {
  union { unsigned u; float f; } v; v.u = pair & 0xFFFF0000u; return v.f;
}

// =================== preprocessing ===================

// fused: count_deg (blocks [0,625)) + prep (blocks [625,3800))
__global__ __launch_bounds__(256) void k_count_prep(
    const int* __restrict__ src, const int* __restrict__ dst, int* deg_src, int* deg_dst,
    const float* __restrict__ gcn1_W, u16* __restrict__ gcn1_Wt,
    const float* __restrict__ gcn2_W, u16* __restrict__ gcn2_Wt,
    const float* __restrict__ gcn3_W, u16* __restrict__ gcn3_Wt,
    const float* __restrict__ gat1_W, u16* __restrict__ gat1_Wt,
    const float* __restrict__ gat2_W, u16* __restrict__ gat2_Wt,
    const float* __restrict__ gat3_W, u16* __restrict__ gat3_Wt,
    const float* __restrict__ h, u16* __restrict__ h_bf,
    const float* __restrict__ al1, const float* __restrict__ ar1,
    const float* __restrict__ al2, const float* __restrict__ ar2,
    const float* __restrict__ al3, const float* __restrict__ ar3,
    float* __restrict__ wl1, float* __restrict__ wr1,
    float* __restrict__ wl2, float* __restrict__ wr2,
    float* __restrict__ wl3, float* __restrict__ wr3) {
  int bb = blockIdx.x, t = threadIdx.x;
  if (bb < 625) {
    int e = bb * 256 + t;
    if (e < EE) {
      atomicAdd(&deg_src[src[e]], 1);
      atomicAdd(&deg_dst[dst[e]], 1);
    }
    return;
  }
  int b = bb - 625;
  if (b < 1920) {
    const float* W; u16* Wt; int K, N, idx;
    if (b < 128)       { W = gcn1_W; Wt = gcn1_Wt; K = 128; N = 256; idx = b * 256 + t; }
    else if (b < 384)  { W = gcn2_W; Wt = gcn2_Wt; K = 256; N = 256; idx = (b - 128) * 256 + t; }
    else if (b < 640)  { W = gcn3_W; Wt = gcn3_Wt; K = 256; N = 256; idx = (b - 384) * 256 + t; }
    else if (b < 896)  { W = gat1_W; Wt = gat1_Wt; K = 128; N = 512; idx = (b - 640) * 256 + t; }
    else if (b < 1408) { W = gat2_W; Wt = gat2_Wt; K = 256; N = 512; idx = (b - 896) * 256 + t; }
    else               { W = gat3_W; Wt = gat3_Wt; K = 256; N = 512; idx = (b - 1408) * 256 + t; }
    int k = idx / N, n = idx - k * N;
    Wt[(size_t)n * K + k] = f2bf(W[idx]);
  } else if (b < 3170) {
    int idx = (b - 1920) * 256 + t;
    float4 v = *(const float4*)&h[(size_t)idx * 4];
    ushort4 o;
    o.x = f2bf(v.x); o.y = f2bf(v.y); o.z = f2bf(v.z); o.w = f2bf(v.w);
    *(ushort4*)&h_bf[(size_t)idx * 4] = o;
  } else {
    int jb = b - 3170;
    const float* W; const float* al; const float* ar; float* wl; float* wr; int K, i;
    if (jb == 0)      { W = gat1_W; al = al1; ar = ar1; wl = wl1; wr = wr1; K = 128; i = t; }
    else if (jb <= 2) { W = gat2_W; al = al2; ar = ar2; wl = wl2; wr = wr2; K = 256; i = (jb - 1) * 256 + t; }
    else              { W = gat3_W; al = al3; ar = ar3; wl = wl3; wr = wr3; K = 256; i = (jb - 3) * 256 + t; }
    int hh = i / K, k = i - hh * K;
    float sl = 0.f, sr = 0.f;
    for (int f = 0; f < HH; f++) {
      float wv = W[(size_t)k * ZW + hh * HH + f];
      sl += wv * al[hh * HH + f];
      sr += wv * ar[hh * HH + f];
    }
    wl[hh * K + k] = sl;
    wr[hh * K + k] = sr;
  }
}

// fused: norms (blocks [0,10)) + single-block scan (block 10)
__global__ __launch_bounds__(1024) void k_norms_scan(
    const int* __restrict__ deg_src, const int* __restrict__ deg_dst,
    const int* __restrict__ gid, float* dsrc, float* ddst, int* gstart, int* row_ptr) {
  if (blockIdx.x < 10) {
    int n = blockIdx.x * 1024 + threadIdx.x;
    if (n < NN) {
      int a = deg_src[n]; if (a < 1) a = 1;
      int b = deg_dst[n]; if (b < 1) b = 1;
      dsrc[n] = 1.0f / sqrtf((float)a);
      ddst[n] = 1.0f / sqrtf((float)b);
      if (n == 0) gstart[gid[0]] = 0;
      else if (gid[n] != gid[n - 1]) gstart[gid[n]] = n;
      if (n == NN - 1) gstart[GG] = NN;
    }
    return;
  }
  // exclusive scan of deg_dst -> row_ptr
  __shared__ int wsum[16];
  __shared__ int carry;
  int lane = threadIdx.x & 63, wid = threadIdx.x >> 6;
  if (threadIdx.x == 0) { carry = 0; row_ptr[0] = 0; }
  __syncthreads();
  for (int base = 0; base < NN; base += 1024) {
    int i = base + threadIdx.x;
    int x = (i < NN) ? deg_dst[i] : 0;
#pragma unroll
    for (int off = 1; off < 64; off <<= 1) {
      int t = __shfl_up(x, off);
      if (lane >= off) x += t;
    }
    if (lane == 63) wsum[wid] = x;
    __syncthreads();
    if (wid == 0 && lane < 16) {
      int y = wsum[lane];
#pragma unroll
      for (int off = 1; off < 16; off <<= 1) {
        int t = __shfl_up(y, off, 16);
        if (lane >= off) y += t;
      }
      wsum[lane] = y;
    }
    __syncthreads();
    int woff = (wid > 0) ? wsum[wid - 1] : 0;
    if (i < NN) row_ptr[i + 1] = carry + woff + x;
    int total = wsum[15];
    __syncthreads();
    if (threadIdx.x == 0) carry += total;
    __syncthreads();
  }
}

__global__ void fill_csr_kernel(const int* __restrict__ src, const int* __restrict__ dst,
                                const int* __restrict__ row_ptr, int* fill, int* csr_src) {
  int e = blockIdx.x * blockDim.x + threadIdx.x;
  if (e < EE) {
    int d = dst[e];
    int p = atomicAdd(&fill[d], 1);
    csr_src[row_ptr[d] + p] = src[e];
  }
}

__global__ __launch_bounds__(64) void sort_rows_kernel(const int* __restrict__ row_ptr,
                                                       int* csr_src) {
  int n = blockIdx.x;
  int s0 = row_ptr[n];
  int L = row_ptr[n + 1] - s0;
  if (L <= 1) return;
  __shared__ int buf[512];
  if (L <= 512) {
    for (int i = threadIdx.x; i < L; i += 64) buf[i] = csr_src[s0 + i];
    __syncthreads();
    for (int i = threadIdx.x; i < L; i += 64) {
      int v = buf[i], r = 0;
      for (int j = 0; j < L; j++) {
        int u = buf[j];
        r += (u < v) || (u == v && j < i);
      }
      csr_src[s0 + r] = v;
    }
  } else if (threadIdx.x == 0) {
    for (int i = s0 + 1; i < s0 + L; i++) {
      int v = csr_src[i], j = i - 1;
      while (j >= s0 && csr_src[j] > v) { csr_src[j + 1] = csr_src[j]; j--; }
      csr_src[j + 1] = v;
    }
  }
}

// =================== device helpers ===================

__device__ inline void dev_gcn_agg(int n, int lane,
    const u16* __restrict__ xb, const float* __restrict__ dsrc, const float* __restrict__ ddst,
    const int* __restrict__ row_ptr, const int* __restrict__ csr_src,
    u16* __restrict__ out, int F) {
  int s0 = row_ptr[n], s1 = row_ptr[n + 1];
  float dd = ddst[n];
  if (F == 256) {
    int bf = lane * 4;
    float a0 = 0, a1 = 0, a2 = 0, a3 = 0;
    int e = s0;
    for (; e + 1 < s1; e += 2) {
      int sA = csr_src[e], sB = csr_src[e + 1];
      float wA = dsrc[sA], wB = dsrc[sB];
      uint2 vA = *(const uint2*)&xb[(size_t)sA * 256 + bf];
      uint2 vB = *(const uint2*)&xb[(size_t)sB * 256 + bf];
      a0 += wA * bflo(vA.x) + wB * bflo(vB.x);
      a1 += wA * bfhi(vA.x) + wB * bfhi(vB.x);
      a2 += wA * bflo(vA.y) + wB * bflo(vB.y);
      a3 += wA * bfhi(vA.y) + wB * bfhi(vB.y);
    }
    if (e < s1) {
      int s = csr_src[e];
      float w = dsrc[s];
      uint2 v = *(const uint2*)&xb[(size_t)s * 256 + bf];
      a0 += w * bflo(v.x); a1 += w * bfhi(v.x);
      a2 += w * bflo(v.y); a3 += w * bfhi(v.y);
    }
    ushort4 o;
    o.x = f2bf(a0 * dd); o.y = f2bf(a1 * dd); o.z = f2bf(a2 * dd); o.w = f2bf(a3 * dd);
    *(ushort4*)&out[(size_t)n * 256 + bf] = o;
  } else {  // F == 128
    int bf = lane * 2;
    float a0 = 0, a1 = 0;
    int e = s0;
    for (; e + 1 < s1; e += 2) {
      int sA = csr_src[e], sB = csr_src[e + 1];
      float wA = dsrc[sA], wB = dsrc[sB];
      unsigned vA = *(const unsigned*)&xb[(size_t)sA * 128 + bf];
      unsigned vB = *(const unsigned*)&xb[(size_t)sB * 128 + bf];
      a0 += wA * bflo(vA) + wB * bflo(vB);
      a1 += wA * bfhi(vA) + wB * bfhi(vB);
    }
    if (e < s1) {
      int s = csr_src[e];
      float w = dsrc[s];
      unsigned v = *(const unsigned*)&xb[(size_t)s * 128 + bf];
      a0 += w * bflo(v); a1 += w * bfhi(v);
    }
    ushort2 o;
    o.x = f2bf(a0 * dd); o.y = f2bf(a1 * dd);
    *(ushort2*)&out[(size_t)n * 128 + bf] = o;
  }
}

__device__ inline void dev_scores(int n, int lane, const float* __restrict__ x,
                                  const float* __restrict__ wl, const float* __restrict__ wr,
                                  float* __restrict__ asrc, float* __restrict__ adst, int K) {
  float a0 = 0, a1 = 0, b0 = 0, b1 = 0;
  for (int k = lane; k < K; k += 64) {
    float xv = x[(size_t)n * K + k];
    a0 += xv * wl[k];
    a1 += xv * wl[K + k];
    b0 += xv * wr[k];
    b1 += xv * wr[K + k];
  }
#pragma unroll
  for (int off = 32; off; off >>= 1) {
    a0 += __shfl_down(a0, off);
    a1 += __shfl_down(a1, off);
    b0 += __shfl_down(b0, off);
    b1 += __shfl_down(b1, off);
  }
  if (lane == 0) {
    asrc[n * 2 + 0] = a0; asrc[n * 2 + 1] = a1;
    adst[n * 2 + 0] = b0; adst[n * 2 + 1] = b1;
  }
}

__device__ inline void dev_alpha(int n, int lane,
    const float* __restrict__ asrc, const float* __restrict__ adst,
    const int* __restrict__ row_ptr, const int* __restrict__ csr_src,
    float* __restrict__ alpha) {
  int s0 = row_ptr[n], s1 = row_ptr[n + 1];
  if (s1 <= s0) return;
  float2 an = *(const float2*)&adst[n * 2];
  float m0 = -INFINITY, m1 = -INFINITY;
  for (int e = s0 + lane; e < s1; e += 64) {
    float2 as = *(const float2*)&asrc[csr_src[e] * 2];
    float e0 = as.x + an.x; e0 = (e0 > 0.f) ? e0 : 0.2f * e0;
    float e1 = as.y + an.y; e1 = (e1 > 0.f) ? e1 : 0.2f * e1;
    m0 = fmaxf(m0, e0); m1 = fmaxf(m1, e1);
  }
#pragma unroll
  for (int off = 32; off; off >>= 1) {
    m0 = fmaxf(m0, __shfl_xor(m0, off));
    m1 = fmaxf(m1, __shfl_xor(m1, off));
  }
  float s0f = 0.f, s1f = 0.f;
  for (int e = s0 + lane; e < s1; e += 64) {
    float2 as = *(const float2*)&asrc[csr_src[e] * 2];
    float e0 = as.x + an.x; e0 = (e0 > 0.f) ? e0 : 0.2f * e0;
    float e1 = as.y + an.y; e1 = (e1 > 0.f) ? e1 : 0.2f * e1;
    s0f += __expf(e0 - m0); s1f += __expf(e1 - m1);
  }
#pragma unroll
  for (int off = 32; off; off >>= 1) {
    s0f += __shfl_xor(s0f, off);
    s1f += __shfl_xor(s1f, off);
  }
  float i0 = (s0f > 0.f) ? 1.f / s0f : 0.f;
  float i1 = (s1f > 0.f) ? 1.f / s1f : 0.f;
  for (int e = s0 + lane; e < s1; e += 64) {
    float2 as = *(const float2*)&asrc[csr_src[e] * 2];
    float e0 = as.x + an.x; e0 = (e0 > 0.f) ? e0 : 0.2f * e0;
    float e1 = as.y + an.y; e1 = (e1 > 0.f) ? e1 : 0.2f * e1;
    float2 o; o.x = __expf(e0 - m0) * i0; o.y = __expf(e1 - m1) * i1;
    *(float2*)&alpha[e * 2] = o;
  }
}

#define BM 128
#define BN 64
#define BK 64
#define LPAD 8

__device__ inline void dev_gemm(const u16* __restrict__ A, const u16* __restrict__ Wt,
                                const float* __restrict__ bias, u16* __restrict__ Cb,
                                int K, int Nc, int relu, int bx, int by, int tid,
                                u16 (*As)[BK + LPAD], u16 (*Bs)[BK + LPAD]) {
  int lane = tid & 63;
  int wid = tid >> 6;
  int wm = wid & 1, wn = wid >> 1;
  int l15 = lane & 15, lg = lane >> 4;
  int row0 = bx * BM;
  int col0 = by * BN;
  f32x4 acc[4][2] = {};
  for (int k0 = 0; k0 < K; k0 += BK) {
#pragma unroll
    for (int p = 0; p < 4; p++) {
      int c = p * 256 + tid;
      int r = c >> 3, k8 = c & 7;
      uint4 v = make_uint4(0, 0, 0, 0);
      int gr = row0 + r;
      if (gr < NN) v = *(const uint4*)&A[(size_t)gr * K + k0 + k8 * 8];
      *(uint4*)&As[r][k8 * 8] = v;
    }
#pragma unroll
    for (int p = 0; p < 2; p++) {
      int c = p * 256 + tid;
      int r = c >> 3, k8 = c & 7;
      uint4 v = *(const uint4*)&Wt[(size_t)(col0 + r) * K + k0 + k8 * 8];
      *(uint4*)&Bs[r][k8 * 8] = v;
    }
    __syncthreads();
#pragma unroll
    for (int ks = 0; ks < BK; ks += 32) {
      bf16x8 afr[4], bfr[2];
#pragma unroll
      for (int m = 0; m < 4; m++)
        afr[m] = *(const bf16x8*)&As[wm * 64 + m * 16 + l15][ks + lg * 8];
#pragma unroll
      for (int n = 0; n < 2; n++)
        bfr[n] = *(const bf16x8*)&Bs[wn * 32 + n * 16 + l15][ks + lg * 8];
#pragma unroll
      for (int m = 0; m < 4; m++)
#pragma unroll
        for (int n = 0; n < 2; n++)
          acc[m][n] = __builtin_amdgcn_mfma_f32_16x16x32_bf16(afr[m], bfr[n], acc[m][n], 0, 0, 0);
    }
    __syncthreads();
  }
#pragma unroll
  for (int m = 0; m < 4; m++) {
#pragma unroll
    for (int n = 0; n < 2; n++) {
      int gc = col0 + wn * 32 + n * 16 + l15;
      float bv = bias ? bias[gc] : 0.f;
#pragma unroll
      for (int j = 0; j < 4; j++) {
        int gr = row0 + wm * 64 + m * 16 + lg * 4 + j;
        if (gr < NN) {
          float v = acc[m][n][j] + bv;
          if (relu) v = fmaxf(v, 0.f);
          Cb[(size_t)gr * Nc + gc] = f2bf(v);
        }
      }
    }
  }
}

__device__ inline void dev_gat_agg(int n, int tid,
    const u16* __restrict__ zb, const float* __restrict__ alpha, const float* __restrict__ b,
    const int* __restrict__ row_ptr, const int* __restrict__ csr_src,
    u16* __restrict__ out_bf,
    const float* __restrict__ wlN, const float* __restrict__ wrN,
    float* __restrict__ asrcN, float* __restrict__ adstN,
    float (*hv)[HH], float (*red)[4]) {
  int h = tid >> 7;       // 0..1
  int p = tid & 127;      // bf16-pair index
  int s0 = row_ptr[n], s1 = row_ptr[n + 1];
  float a0 = 0.f, a1 = 0.f;
  int e = s0;
  for (; e + 1 < s1; e += 2) {
    int sA = csr_src[e], sB = csr_src[e + 1];
    float wA = alpha[e * 2 + h], wB = alpha[(e + 1) * 2 + h];
    unsigned zA = *(const unsigned*)&zb[(size_t)sA * ZW + h * HH + p * 2];
    unsigned zB = *(const unsigned*)&zb[(size_t)sB * ZW + h * HH + p * 2];
    a0 += wA * bflo(zA) + wB * bflo(zB);
    a1 += wA * bfhi(zA) + wB * bfhi(zB);
  }
  if (e < s1) {
    int s = csr_src[e];
    float w = alpha[e * 2 + h];
    unsigned zv = *(const unsigned*)&zb[(size_t)s * ZW + h * HH + p * 2];
    a0 += w * bflo(zv);
    a1 += w * bfhi(zv);
  }
  float r0 = fmaxf(a0 + b[h * HH + p * 2 + 0], 0.f);
  float r1 = fmaxf(a1 + b[h * HH + p * 2 + 1], 0.f);
  hv[h][p * 2 + 0] = r0;
  hv[h][p * 2 + 1] = r1;
  __syncthreads();
  float o = 0.5f * (hv[0][tid] + hv[1][tid]);
  out_bf[(size_t)n * HH + tid] = f2bf(o);
  if (wlN) {
    float p0 = o * wlN[tid], p1 = o * wlN[256 + tid];
    float q0 = o * wrN[tid], q1 = o * wrN[256 + tid];
    int lane = tid & 63, wid = tid >> 6;
#pragma unroll
    for (int off = 32; off; off >>= 1) {
      p0 += __shfl_down(p0, off);
      p1 += __shfl_down(p1, off);
      q0 += __shfl_down(q0, off);
      q1 += __shfl_down(q1, off);
    }
    if (lane == 0) { red[wid][0] = p0; red[wid][1] = p1; red[wid][2] = q0; red[wid][3] = q1; }
    __syncthreads();
    if (tid == 0) {
      asrcN[n * 2 + 0] = red[0][0] + red[1][0] + red[2][0] + red[3][0];
      asrcN[n * 2 + 1] = red[0][1] + red[1][1] + red[2][1] + red[3][1];
      adstN[n * 2 + 0] = red[0][2] + red[1][2] + red[2][2] + red[3][2];
      adstN[n * 2 + 1] = red[0][3] + red[1][3] + red[2][3] + red[3][3];
    }
  }
}

__device__ inline void dev_stage1(const u16* __restrict__ x, int l, int g, int s, int f,
                                  const int* __restrict__ gstart, float* __restrict__ partial) {
  int n0 = gstart[g], n1 = gstart[g + 1];
  int cnt = n1 - n0;
  int chunk = (cnt + RS - 1) / RS;
  int a = n0 + s * chunk;
  int bnd = a + chunk; if (bnd > n1) bnd = n1;
  float sum = 0.f, mx = -INFINITY;
  for (int n = a; n < bnd; n++) {
    float v = bf2f(x[(size_t)n * HH + f]);
    sum += v;
    mx = fmaxf(mx, v);
  }
  size_t base = ((size_t)l * GG * RS + g * RS + s) * 2 * HH;
  partial[base + f] = sum;
  partial[base + HH + f] = mx;
}

__device__ inline void dev_stage2(const float* __restrict__ partial, int l, int g, int t,
                                  const int* __restrict__ gstart, float* __restrict__ rr) {
  int f = t & 255, ismax = t >> 8;
  size_t base = ((size_t)l * GG * RS + g * RS) * 2 * HH;
  if (!ismax) {
    float s = 0.f;
    for (int k = 0; k < RS; k++) s += partial[base + (size_t)k * 2 * HH + f];
    rr[(size_t)l * GG * 512 + g * 512 + f] = s / (float)(gstart[g + 1] - gstart[g]);
  } else {
    float m = -INFINITY;
    for (int k = 0; k < RS; k++) m = fmaxf(m, partial[base + (size_t)k * 2 * HH + HH + f]);
    rr[(size_t)l * GG * 512 + g * 512 + 256 + f] = m;
  }
}

// =================== fused stage kernels ===================

// S1: gcn_agg(h_bf, F=128) blocks [0,2500) + scores1(h fp32) blocks [2500,5000)
__global__ __launch_bounds__(256) void k_s1(
    const u16* __restrict__ h_bf, const float* __restrict__ h,
    const float* __restrict__ dsrc, const float* __restrict__ ddst,
    const int* __restrict__ row_ptr, const int* __restrict__ csr_src,
    u16* __restrict__ zagg, const float* __restrict__ wl1, const float* __restrict__ wr1,
    float* __restrict__ asrc, float* __restrict__ adst) {
  int b = blockIdx.x, t = threadIdx.x;
  int wid = t >> 6, lane = t & 63;
  if (b < 2500) {
    int n = b * 4 + wid;
    if (n < NN) dev_gcn_agg(n, lane, h_bf, dsrc, ddst, row_ptr, csr_src, zagg, FIN);
  } else {
    int n = (b - 2500) * 4 + wid;
    if (n < NN) dev_scores(n, lane, h, wl1, wr1, asrc, adst, FIN);
  }
}

// SG: gcn gemm (blocks [0,316)) + gat gemm (blocks [316,948)) + alpha (blocks [948,3448))
__global__ __launch_bounds__(256) void k_gemms(
    const u16* __restrict__ A1, const u16* __restrict__ Wt1, const float* __restrict__ bias1,
    u16* __restrict__ C1, int K1,
    const u16* __restrict__ A2, const u16* __restrict__ Wt2, u16* __restrict__ C2, int K2,
    const float* __restrict__ asrc, const float* __restrict__ adst,
    const int* __restrict__ row_ptr, const int* __restrict__ csr_src,
    float* __restrict__ alpha) {
  __shared__ u16 As[BM][BK + LPAD];
  __shared__ u16 Bs[BN][BK + LPAD];
  int b = blockIdx.x, t = threadIdx.x;
  if (b < 316) {
    dev_gemm(A1, Wt1, bias1, C1, K1, HH, 1, b % 79, b / 79, t, As, Bs);
  } else if (b < 948) {
    int i = b - 316;
    dev_gemm(A2, Wt2, nullptr, C2, K2, ZW, 0, i % 79, i / 79, t, As, Bs);
  } else {
    int n = (b - 948) * 4 + (t >> 6);
    if (n < NN) dev_alpha(n, t & 63, asrc, adst, row_ptr, csr_src, alpha);
  }
}

// S3: gat_agg blocks [0,10000) + gcn_agg(F=256) blocks [10000,12500)
__global__ __launch_bounds__(256) void k_s3(
    const u16* __restrict__ zb, const float* __restrict__ alpha, const float* __restrict__ gb,
    const int* __restrict__ row_ptr, const int* __restrict__ csr_src,
    u16* __restrict__ out_bf,
    const float* __restrict__ wlN, const float* __restrict__ wrN,
    float* __restrict__ asrcN, float* __restrict__ adstN,
    const u16* __restrict__ xb, const float* __restrict__ dsrc, const float* __restrict__ ddst,
    u16* __restrict__ zagg) {
  __shared__ float hv[2][HH];
  __shared__ float red[4][4];
  int b = blockIdx.x, t = threadIdx.x;
  if (b < 10000) {
    dev_gat_agg(b, t, zb, alpha, gb, row_ptr, csr_src, out_bf, wlN, wrN, asrcN, adstN, hv, red);
  } else {
    int n = (b - 10000) * 4 + (t >> 6);
    if (n < NN) dev_gcn_agg(n, t & 63, xb, dsrc, ddst, row_ptr, csr_src, zagg, HH);
  }
}

// S7: gat_agg3 blocks [0,10000) + stage1 for layers 0..3 blocks [10000,12048)
struct Acts4 { const u16* a[4]; };
__global__ __launch_bounds__(256) void k_s7(
    const u16* __restrict__ zb, const float* __restrict__ alpha, const float* __restrict__ gb,
    const int* __restrict__ row_ptr, const int* __restrict__ csr_src,
    u16* __restrict__ out_bf,
    Acts4 acts, const int* __restrict__ gstart, float* __restrict__ partial) {
  __shared__ float hv[2][HH];
  __shared__ float red[4][4];
  int b = blockIdx.x, t = threadIdx.x;
  if (b < 10000) {
    dev_gat_agg(b, t, zb, alpha, gb, row_ptr, csr_src, out_bf,
                nullptr, nullptr, nullptr, nullptr, hv, red);
  } else {
    int i = b - 10000;
    int l = i >> 9, rem = i & 511;
    dev_stage1(acts.a[l], l, rem >> 3, rem & 7, t, gstart, partial);
  }
}

// S8: stage1 layer4 blocks [0,512) + stage2 layers 0..3 blocks [512,768)
__global__ __launch_bounds__(512) void k_s8(
    const u16* __restrict__ gb3, const int* __restrict__ gstart,
    float* __restrict__ partial, float* __restrict__ rr) {
  int b = blockIdx.x, t = threadIdx.x;
  if (b < 512) {
    if (t < 256) dev_stage1(gb3, 4, b >> 3, b & 7, t, gstart, partial);
  } else {
    int j = b - 512;
    dev_stage2(partial, j >> 6, j & 63, t, gstart, rr);
  }
}

// S9: stage2 layer4
__global__ __launch_bounds__(512) void k_s9(
    const float* __restrict__ partial, const int* __restrict__ gstart, float* __restrict__ rr) {
  dev_stage2(partial, 4, blockIdx.x, threadIdx.x, gstart, rr);
}

// ---------------- FC head with assemble fused ----------------
__global__ __launch_bounds__(128) void fc_head_kernel(
    const float* __restrict__ rr, const float* __restrict__ W1, const float* __restrict__ b1,
    const float* __restrict__ W2, const float* __restrict__ b2, float* __restrict__ out) {
  int g = blockIdx.x;
  int t = threadIdx.x;
  __shared__ float row[1024];
  __shared__ float f1[128];
  const float* R0 = rr + 0 * GG * 512 + g * 512;
  const float* R1 = rr + 1 * GG * 512 + g * 512;
  const float* R2 = rr + 2 * GG * 512 + g * 512;
  const float* R3 = rr + 3 * GG * 512 + g * 512;
  const float* R4 = rr + 4 * GG * 512 + g * 512;
  for (int c = t; c < 512; c += 128) {
    float spec = R0[c] + R1[c] + R2[c];
    float s3 = (c < 256) ? R3[c] : R4[c];
    float spat = R0[c] + R3[c] + s3;
    row[c] = spec;
    row[512 + c] = spat;
  }
  __syncthreads();
  float acc = b1[t];
  for (int k = 0; k < 1024; k++) acc += row[k] * W1[k * 128 + t];
  f1[t] = fmaxf(acc, 0.f);
  __syncthreads();
  if (t < 2) {
    float a = b2[t];
    for (int k = 0; k < 128; k++) a += f1[k] * W2[k * 2 + t];
    out[g * 2 + t] = 1.f / (1.f + expf(-a));
  }
}

extern "C" void kernel_launch(void* const* d_in, const int* in_sizes, int n_in,
                              void* d_out, int out_size, void* d_ws, size_t ws_size,
                              hipStream_t stream) {
  const float* h      = (const float*)d_in[0];
  const int*   src    = (const int*)d_in[1];
  const int*   dst    = (const int*)d_in[2];
  const int*   gid    = (const int*)d_in[3];
  const float* gcn1_W = (const float*)d_in[4];  const float* gcn1_b = (const float*)d_in[5];
  const float* gcn2_W = (const float*)d_in[6];  const float* gcn2_b = (const float*)d_in[7];
  const float* gcn3_W = (const float*)d_in[8];  const float* gcn3_b = (const float*)d_in[9];
  const float* gat1_W = (const float*)d_in[10]; const float* gat1_al = (const float*)d_in[11];
  const float* gat1_ar= (const float*)d_in[12]; const float* gat1_b = (const float*)d_in[13];
  const float* gat2_W = (const float*)d_in[14]; const float* gat2_al = (const float*)d_in[15];
  const float* gat2_ar= (const float*)d_in[16]; const float* gat2_b = (const float*)d_in[17];
  const float* gat3_W = (const float*)d_in[18]; const float* gat3_al = (const float*)d_in[19];
  const float* gat3_ar= (const float*)d_in[20]; const float* gat3_b = (const float*)d_in[21];
  const float* fc1_W  = (const float*)d_in[22]; const float* fc1_b = (const float*)d_in[23];
  const float* fc2_W  = (const float*)d_in[24]; const float* fc2_b = (const float*)d_in[25];

  char* ws = (char*)d_ws;
  size_t off = 0;
  auto alloc = [&](size_t bytes) -> void* {
    void* p = ws + off;
    off += (bytes + 255) & ~(size_t)255;
    return p;
  };
  u16*   Zb      = (u16*)alloc((size_t)NN * ZW * 2);
  u16*   Zagg_bf = (u16*)alloc((size_t)NN * HH * 2);
  u16*   h_bf    = (u16*)alloc((size_t)NN * FIN * 2);
  u16*   ab1     = (u16*)alloc((size_t)NN * HH * 2);
  u16*   ab2     = (u16*)alloc((size_t)NN * HH * 2);
  u16*   ab3     = (u16*)alloc((size_t)NN * HH * 2);
  u16*   gb1     = (u16*)alloc((size_t)NN * HH * 2);
  u16*   gb2     = (u16*)alloc((size_t)NN * HH * 2);
  u16*   gb3     = (u16*)alloc((size_t)NN * HH * 2);
  int*   row_ptr = (int*)alloc((NN + 1) * 4);
  int*   csr_src = (int*)alloc((size_t)EE * 4);
  int*   meta    = (int*)alloc((size_t)3 * NN * 4);
  int*   deg_src = meta;
  int*   deg_dst = meta + NN;
  int*   fill    = meta + 2 * NN;
  float* dsrc    = (float*)alloc(NN * 4);
  float* ddst    = (float*)alloc(NN * 4);
  int*   gstart  = (int*)alloc((GG + 1) * 4);
  float* asrc    = (float*)alloc(NN * 2 * 4);
  float* adst    = (float*)alloc(NN * 2 * 4);
  float* alpha   = (float*)alloc((size_t)EE * 2 * 4);
  float* wl1     = (float*)alloc(2 * FIN * 4);
  float* wr1     = (float*)alloc(2 * FIN * 4);
  float* wl2     = (float*)alloc(2 * HH * 4);
  float* wr2     = (float*)alloc(2 * HH * 4);
  float* wl3     = (float*)alloc(2 * HH * 4);
  float* wr3     = (float*)alloc(2 * HH * 4);
  float* partial = (float*)alloc((size_t)5 * GG * RS * 2 * HH * 4);
  float* rr      = (float*)alloc((size_t)5 * GG * 512 * 4);
  u16* gcn1_Wt = (u16*)alloc((size_t)FIN * HH * 2);
  u16* gcn2_Wt = (u16*)alloc((size_t)HH * HH * 2);
  u16* gcn3_Wt = (u16*)alloc((size_t)HH * HH * 2);
  u16* gat1_Wt = (u16*)alloc((size_t)FIN * ZW * 2);
  u16* gat2_Wt = (u16*)alloc((size_t)HH * ZW * 2);
  u16* gat3_Wt = (u16*)alloc((size_t)HH * ZW * 2);

  // preprocessing
  hipMemsetAsync(meta, 0, (size_t)3 * NN * 4, stream);
  k_count_prep<<<3800, 256, 0, stream>>>(
      src, dst, deg_src, deg_dst,
      gcn1_W, gcn1_Wt, gcn2_W, gcn2_Wt, gcn3_W, gcn3_Wt,
      gat1_W, gat1_Wt, gat2_W, gat2_Wt, gat3_W, gat3_Wt,
      h, h_bf,
      gat1_al, gat1_ar, gat2_al, gat2_ar, gat3_al, gat3_ar,
      wl1, wr1, wl2, wr2, wl3, wr3);
  k_norms_scan<<<11, 1024, 0, stream>>>(deg_src, deg_dst, gid, dsrc, ddst, gstart, row_ptr);
  fill_csr_kernel<<<625, 256, 0, stream>>>(src, dst, row_ptr, fill, csr_src);
  sort_rows_kernel<<<NN, 64, 0, stream>>>(row_ptr, csr_src);

  // layer 1
  k_s1<<<5000, 256, 0, stream>>>(h_bf, h, dsrc, ddst, row_ptr, csr_src, Zagg_bf,
                                 wl1, wr1, asrc, adst);
  k_gemms<<<3448, 256, 0, stream>>>(Zagg_bf, gcn1_Wt, gcn1_b, ab1, FIN,
                                    h_bf, gat1_Wt, Zb, FIN,
                                    asrc, adst, row_ptr, csr_src, alpha);
  k_s3<<<12500, 256, 0, stream>>>(Zb, alpha, gat1_b, row_ptr, csr_src, gb1,
                                  wl2, wr2, asrc, adst,
                                  ab1, dsrc, ddst, Zagg_bf);
  // layer 2
  k_gemms<<<3448, 256, 0, stream>>>(Zagg_bf, gcn2_Wt, gcn2_b, ab2, HH,
                                    gb1, gat2_Wt, Zb, HH,
                                    asrc, adst, row_ptr, csr_src, alpha);
  k_s3<<<12500, 256, 0, stream>>>(Zb, alpha, gat2_b, row_ptr, csr_src, gb2,
                                  wl3, wr3, asrc, adst,
                                  ab2, dsrc, ddst, Zagg_bf);
  // layer 3
  k_gemms<<<3448, 256, 0, stream>>>(Zagg_bf, gcn3_Wt, gcn3_b, ab3, HH,
                                    gb2, gat3_Wt, Zb, HH,
                                    asrc, adst, row_ptr, csr_src, alpha);
  Acts4 acts;
  acts.a[0] = ab1; acts.a[1] = ab2; acts.a[2] = ab3; acts.a[3] = gb2;
  k_s7<<<12048, 256, 0, stream>>>(Zb, alpha, gat3_b, row_ptr, csr_src, gb3,
                                  acts, gstart, partial);
  k_s8<<<768, 512, 0, stream>>>(gb3, gstart, partial, rr);
  k_s9<<<GG, 512, 0, stream>>>(partial, gstart, rr);
  fc_head_kernel<<<GG, 128, 0, stream>>>(rr, fc1_W, fc1_b, fc2_W, fc2_b, (float*)d_out);
}